// Round 1
// baseline (372.529 us; speedup 1.0000x reference)
//
#include <hip/hip_runtime.h>
#include <hip/hip_bf16.h>

typedef __hip_bfloat16 bf16;

#define B_   2048
#define S_   40
#define NTOK (B_*S_)

__device__ inline unsigned pk2(float a, float b){
    __hip_bfloat16 ha = __float2bfloat16(a), hb = __float2bfloat16(b);
    unsigned short ua = *reinterpret_cast<unsigned short*>(&ha);
    unsigned short ub = *reinterpret_cast<unsigned short*>(&hb);
    return (unsigned)ua | ((unsigned)ub << 16);
}

// ---------------- Kernel 1: per-token featurizer + K/V projection ----------------
__global__ __launch_bounds__(64) void k_token(
    const float* __restrict__ X,
    const float* __restrict__ emb_act,
    const float* __restrict__ emb_zone,
    const float* __restrict__ lin0_W, const float* __restrict__ lin0_b,
    const float* __restrict__ gat_W,  const float* __restrict__ gat_b,
    const float* __restrict__ gat_a,
    const float* __restrict__ gl0_W,  const float* __restrict__ gl0_b,
    const float* __restrict__ gl1_W,  const float* __restrict__ gl1_b,
    const float* __restrict__ gl2_W,  const float* __restrict__ gl2_b,
    const float* __restrict__ Wqkv,   const float* __restrict__ bqkv,
    bf16* __restrict__ kv, float* __restrict__ src_last)
{
    __shared__ float sff[64*111];   // per-thread 110-elem ff row, stride 111 (bank-friendly)
    __shared__ float shead[64*8];   // cols 0..7 of X row

    const int t   = threadIdx.x;
    const int tok = blockIdx.x * 64 + t;
    const int b   = tok / 40;
    const int s   = tok - b * 40;

    float* ff = &sff[t*111];
    float* hd = &shead[t*8];

    // load own row (8-byte aligned: 118*4 and +32 are both multiples of 8)
    {
        const float2* xp = (const float2*)(X + (size_t)tok * 118);
        #pragma unroll
        for (int p = 0; p < 4; ++p){ float2 v = xp[p]; hd[2*p] = v.x; hd[2*p+1] = v.y; }
        #pragma unroll
        for (int p = 0; p < 55; ++p){ float2 v = xp[4+p]; ff[2*p] = v.x; ff[2*p+1] = v.y; }
    }

    // ---- GAT: s1_j = ff_j . (gat_W @ a1) + gat_b.a1 ; same for s2 ----
    float va1[5], va2[5];
    float c1 = 0.f, c2 = 0.f;
    #pragma unroll
    for (int e = 0; e < 5; ++e){
        float u1 = 0.f, u2 = 0.f;
        #pragma unroll
        for (int d = 0; d < 5; ++d){
            u1 += gat_W[e*5+d] * gat_a[d];
            u2 += gat_W[e*5+d] * gat_a[5+d];
        }
        va1[e] = u1; va2[e] = u2;
    }
    #pragma unroll
    for (int d = 0; d < 5; ++d){ c1 += gat_b[d]*gat_a[d]; c2 += gat_b[d]*gat_a[5+d]; }

    // m2 = max_j s2_j  (leaky_relu is monotonic -> row max = leaky(s1_i + m2))
    float m2 = -1e30f;
    for (int j = 0; j < 22; ++j){
        float t2 = c2;
        #pragma unroll
        for (int e = 0; e < 5; ++e) t2 += ff[j*5+e]*va2[e];
        m2 = fmaxf(m2, t2);
    }

    // pre0[c] = gl0_b[c] + sum_i sum_d hp_i[d] * gl0_W[(5i+d)][c]
    float pre0[64];
    #pragma unroll
    for (int c = 0; c < 64; ++c) pre0[c] = gl0_b[c];

    for (int i = 0; i < 22; ++i){
        float s1i = c1;
        #pragma unroll
        for (int e = 0; e < 5; ++e) s1i += ff[i*5+e]*va1[e];
        float ei = s1i + m2;
        float mi = ei > 0.f ? ei : 0.2f*ei;

        float Z = 0.f;
        float ffp[5] = {0.f,0.f,0.f,0.f,0.f};
        for (int j = 0; j < 22; ++j){
            float s2j = c2;
            #pragma unroll
            for (int e = 0; e < 5; ++e) s2j += ff[j*5+e]*va2[e];
            float e2 = s1i + s2j;
            float l  = e2 > 0.f ? e2 : 0.2f*e2;
            float w  = __expf(l - mi);
            Z += w;
            #pragma unroll
            for (int e = 0; e < 5; ++e) ffp[e] += w * ff[j*5+e];
        }
        float rz = 1.f / Z;
        float hp[5];
        #pragma unroll
        for (int d = 0; d < 5; ++d){
            float u = 0.f;
            #pragma unroll
            for (int e = 0; e < 5; ++e) u += ffp[e]*gat_W[e*5+d];
            hp[d] = u*rz + gat_b[d];
        }
        #pragma unroll
        for (int d = 0; d < 5; ++d){
            const float* w = &gl0_W[(i*5+d)*64];
            float h = hp[d];
            #pragma unroll
            for (int c = 0; c < 64; ++c) pre0[c] = fmaf(h, w[c], pre0[c]);
        }
    }

    // gl1: 64 -> 64
    #pragma unroll
    for (int c = 0; c < 64; ++c) ff[c] = fmaxf(pre0[c], 0.f);
    float pre1[64];
    #pragma unroll
    for (int c = 0; c < 64; ++c) pre1[c] = gl1_b[c];
    for (int k = 0; k < 64; ++k){
        float f = ff[k];
        const float* w = &gl1_W[k*64];
        #pragma unroll
        for (int c = 0; c < 64; ++c) pre1[c] = fmaf(f, w[c], pre1[c]);
    }

    // gl2: 64 -> 16
    #pragma unroll
    for (int c = 0; c < 64; ++c) ff[c] = fmaxf(pre1[c], 0.f);
    float pre2[16];
    #pragma unroll
    for (int c = 0; c < 16; ++c) pre2[c] = gl2_b[c];
    for (int k = 0; k < 64; ++k){
        float f = ff[k];
        const float* w = &gl2_W[k*16];
        #pragma unroll
        for (int c = 0; c < 16; ++c) pre2[c] = fmaf(f, w[c], pre2[c]);
    }

    // od = other @ lin0_W + lin0_b
    float od[16];
    #pragma unroll
    for (int c = 0; c < 16; ++c) od[c] = lin0_b[c];
    #pragma unroll
    for (int e = 0; e < 6; ++e){
        float f = hd[2+e];
        #pragma unroll
        for (int c = 0; c < 16; ++c) od[c] = fmaf(f, lin0_W[e*16+c], od[c]);
    }

    // positional encoding: ang = b / 100^(2s/40); even s -> sin, odd -> cos
    float expo  = (2.0f * (float)s) / 40.0f;
    float denom = powf(100.0f, expo);
    float ang   = (float)b / denom;
    float pe    = ((s & 1) == 0) ? sinf(ang) : cosf(ang);

    int ia = (int)hd[0], iz = (int)hd[1];
    float src[64];
    #pragma unroll
    for (int c = 0; c < 16; ++c) src[c]      = emb_act[ia*16+c]  + pe;
    #pragma unroll
    for (int c = 0; c < 16; ++c) src[16+c]   = emb_zone[iz*16+c] + pe;
    #pragma unroll
    for (int c = 0; c < 16; ++c) src[32+c]   = od[c] + pe;
    #pragma unroll
    for (int c = 0; c < 16; ++c) src[48+c]   = fmaxf(pre2[c], 0.f) + pe;

    if (s == 39){
        float* sl = src_last + b*64;
        #pragma unroll
        for (int c = 0; c < 64; ++c) sl[c] = src[c];
    }

    // K,V projection: cols 64..191 of Wqkv
    #pragma unroll
    for (int c = 0; c < 64; ++c) ff[c] = src[c];
    float acc[128];
    #pragma unroll
    for (int c = 0; c < 128; ++c) acc[c] = bqkv[64+c];
    for (int d = 0; d < 64; ++d){
        float f = ff[d];
        const float* w = &Wqkv[d*192 + 64];
        #pragma unroll
        for (int c = 0; c < 128; ++c) acc[c] = fmaf(f, w[c], acc[c]);
    }

    uint4* o4 = (uint4*)(kv + (size_t)tok * 128);
    #pragma unroll
    for (int g = 0; g < 16; ++g){
        uint4 u;
        u.x = pk2(acc[8*g+0], acc[8*g+1]);
        u.y = pk2(acc[8*g+2], acc[8*g+3]);
        u.z = pk2(acc[8*g+4], acc[8*g+5]);
        u.w = pk2(acc[8*g+6], acc[8*g+7]);
        o4[g] = u;
    }
}

// ---------------- Kernel 2: per-batch attention@last + FFN + heads ----------------
__global__ __launch_bounds__(128) void k_head(
    const bf16* __restrict__ kv, const float* __restrict__ src_last,
    const float* __restrict__ Wqkv, const float* __restrict__ bqkv,
    const float* __restrict__ Wo,   const float* __restrict__ bo,
    const float* __restrict__ ln1_g, const float* __restrict__ ln1_b,
    const float* __restrict__ W1,   const float* __restrict__ b1,
    const float* __restrict__ W2,   const float* __restrict__ b2,
    const float* __restrict__ ln2_g, const float* __restrict__ ln2_b,
    const float* __restrict__ relu_W, const float* __restrict__ relu_b,
    const float* __restrict__ nd_W, const float* __restrict__ nd_b,
    const float* __restrict__ ldt_W, const float* __restrict__ ldt_b,
    const float* __restrict__ nz_W, const float* __restrict__ nz_b,
    const float* __restrict__ lz_W, const float* __restrict__ lz_b,
    const float* __restrict__ na0_W, const float* __restrict__ na0_b,
    const float* __restrict__ na1_W, const float* __restrict__ na1_b,
    const float* __restrict__ la_W, const float* __restrict__ la_b,
    float* __restrict__ out)
{
    const int b = blockIdx.x, t = threadIdx.x;
    __shared__ float kb[40][64];
    __shared__ float vb[40][64];
    __shared__ float qs[64], xb[64], yb[64], f1[256];
    __shared__ float xrs[64], m65[65], mzs[20], fa1[85], fa2[85], redv[1];

    // load K,V (bf16 pairs packed in uint32)
    {
        const unsigned* kv32 = (const unsigned*)(kv + (size_t)b * 40 * 128);
        for (int idx = t; idx < 2560; idx += 128){
            unsigned u = kv32[idx];
            int j  = idx >> 6;
            int cp = (idx & 63) << 1;
            float lo = __uint_as_float(u << 16);
            float hi = __uint_as_float(u & 0xffff0000u);
            if (cp < 64){ kb[j][cp] = lo; kb[j][cp+1] = hi; }
            else        { vb[j][cp-64] = lo; vb[j][cp-63] = hi; }
        }
    }
    if (t < 64) xb[t] = src_last[b*64 + t];
    __syncthreads();

    // q at last position, pre-scaled by 1/sqrt(8)
    if (t < 64){
        float a = bqkv[t];
        for (int d = 0; d < 64; ++d) a += xb[d]*Wqkv[d*192 + t];
        qs[t] = a * 0.35355339059327373f;
    }
    __syncthreads();

    // attention: thread t computes o[t]; head h = t>>3
    float o_c = 0.f;
    if (t < 64){
        const int h = t >> 3;
        const float* qh = &qs[h*8];
        float sc[40];
        float m = -1e30f;
        #pragma unroll
        for (int j = 0; j < 40; ++j){
            float a = 0.f;
            #pragma unroll
            for (int d = 0; d < 8; ++d) a += qh[d]*kb[j][h*8+d];
            sc[j] = a; m = fmaxf(m, a);
        }
        float Z = 0.f, acc = 0.f;
        #pragma unroll
        for (int j = 0; j < 40; ++j){
            float w = __expf(sc[j] - m);
            Z += w; acc += w * vb[j][t];
        }
        o_c = acc / Z;
    }
    if (t < 64) yb[t] = o_c;
    __syncthreads();

    // Wo + residual + LN1 -> xb
    float x1 = 0.f;
    if (t < 64){
        float a = bo[t];
        for (int d = 0; d < 64; ++d) a += yb[d]*Wo[d*64+t];
        float v = xb[t] + a;
        float sum = v;
        #pragma unroll
        for (int off = 1; off < 64; off <<= 1) sum += __shfl_xor(sum, off, 64);
        float mean = sum * (1.f/64.f);
        float dd = v - mean;
        float s2 = dd*dd;
        #pragma unroll
        for (int off = 1; off < 64; off <<= 1) s2 += __shfl_xor(s2, off, 64);
        float var = s2 * (1.f/64.f);
        x1 = dd * rsqrtf(var + 1e-5f) * ln1_g[t] + ln1_b[t];
    }
    __syncthreads();
    if (t < 64) xb[t] = x1;
    __syncthreads();

    // FFN 64 -> 256 (relu)
    for (int c = t; c < 256; c += 128){
        float a = b1[c];
        for (int d = 0; d < 64; ++d) a += xb[d]*W1[d*256+c];
        f1[c] = fmaxf(a, 0.f);
    }
    __syncthreads();

    // 256 -> 64, residual + LN2 -> yb
    if (t < 64){
        float a = b2[t];
        for (int j = 0; j < 256; ++j) a += f1[j]*W2[j*64+t];
        float v = xb[t] + a;
        float sum = v;
        #pragma unroll
        for (int off = 1; off < 64; off <<= 1) sum += __shfl_xor(sum, off, 64);
        float mean = sum * (1.f/64.f);
        float dd = v - mean;
        float s2 = dd*dd;
        #pragma unroll
        for (int off = 1; off < 64; off <<= 1) s2 += __shfl_xor(s2, off, 64);
        float var = s2 * (1.f/64.f);
        yb[t] = dd * rsqrtf(var + 1e-5f) * ln2_g[t] + ln2_b[t];
    }
    __syncthreads();

    // xr = x2 @ relu_W + relu_b   (no activation, per reference)
    if (t < 64){
        float a = relu_b[t];
        for (int d = 0; d < 64; ++d) a += yb[d]*relu_W[d*64+t];
        xrs[t] = a;
    }
    __syncthreads();

    // nd = xr @ nd_W + nd_b ; dT = nd @ ldt_W + ldt_b
    if (t < 64){
        float a = nd_b[t];
        for (int d = 0; d < 64; ++d) a += xrs[d]*nd_W[d*64+t];
        float contrib = a * ldt_W[t];
        #pragma unroll
        for (int off = 1; off < 64; off <<= 1) contrib += __shfl_xor(contrib, off, 64);
        if (t == 0) redv[0] = contrib + ldt_b[0];
    }
    __syncthreads();
    float dT = redv[0];

    // mzpre = [dT, xr] @ nz_W + nz_b  (65 wide)
    if (t < 65){
        float a = nz_b[t] + dT*nz_W[t];
        for (int d = 0; d < 64; ++d) a += xrs[d]*nz_W[(1+d)*65+t];
        m65[t] = a;
    }
    __syncthreads();

    // mz = mzpre @ lz_W + lz_b (20 wide)
    if (t < 20){
        float a = lz_b[t];
        for (int d = 0; d < 65; ++d) a += m65[d]*lz_W[d*20+t];
        mzs[t] = a;
    }
    __syncthreads();

    // fa = [mz(20), dT, xr(64)] -> na0 -> na1 -> la
    if (t < 85){
        float a = na0_b[t];
        for (int d = 0; d < 20; ++d) a += mzs[d]*na0_W[d*85+t];
        a += dT*na0_W[20*85+t];
        for (int d = 0; d < 64; ++d) a += xrs[d]*na0_W[(21+d)*85+t];
        fa1[t] = a;
    }
    __syncthreads();
    if (t < 85){
        float a = na1_b[t];
        for (int d = 0; d < 85; ++d) a += fa1[d]*na1_W[d*85+t];
        fa2[t] = a;
    }
    __syncthreads();

    if (t == 0) out[b*26] = dT;
    if (t < 20) out[b*26 + 1 + t] = mzs[t];
    if (t < 5){
        float a = la_b[t];
        for (int d = 0; d < 85; ++d) a += fa2[d]*la_W[d*5+t];
        out[b*26 + 21 + t] = a;
    }
}

extern "C" void kernel_launch(void* const* d_in, const int* in_sizes, int n_in,
                              void* d_out, int out_size, void* d_ws, size_t ws_size,
                              hipStream_t stream)
{
    const float* X        = (const float*)d_in[0];
    const float* emb_act  = (const float*)d_in[1];
    const float* emb_zone = (const float*)d_in[2];
    const float* lin0_W   = (const float*)d_in[3];
    const float* lin0_b   = (const float*)d_in[4];
    const float* gat_W    = (const float*)d_in[5];
    const float* gat_b    = (const float*)d_in[6];
    const float* gat_a    = (const float*)d_in[7];
    const float* gl0_W    = (const float*)d_in[8];
    const float* gl0_b    = (const float*)d_in[9];
    const float* gl1_W    = (const float*)d_in[10];
    const float* gl1_b    = (const float*)d_in[11];
    const float* gl2_W    = (const float*)d_in[12];
    const float* gl2_b    = (const float*)d_in[13];
    const float* Wqkv     = (const float*)d_in[14];
    const float* bqkv     = (const float*)d_in[15];
    const float* Wo       = (const float*)d_in[16];
    const float* bo       = (const float*)d_in[17];
    const float* ln1_g    = (const float*)d_in[18];
    const float* ln1_b    = (const float*)d_in[19];
    const float* W1       = (const float*)d_in[20];
    const float* b1       = (const float*)d_in[21];
    const float* W2       = (const float*)d_in[22];
    const float* b2       = (const float*)d_in[23];
    const float* ln2_g    = (const float*)d_in[24];
    const float* ln2_b    = (const float*)d_in[25];
    const float* relu_W   = (const float*)d_in[26];
    const float* relu_b   = (const float*)d_in[27];
    const float* nd_W     = (const float*)d_in[28];
    const float* nd_b     = (const float*)d_in[29];
    const float* ldt_W    = (const float*)d_in[30];
    const float* ldt_b    = (const float*)d_in[31];
    const float* nz_W     = (const float*)d_in[32];
    const float* nz_b     = (const float*)d_in[33];
    const float* lz_W     = (const float*)d_in[34];
    const float* lz_b     = (const float*)d_in[35];
    const float* na0_W    = (const float*)d_in[36];
    const float* na0_b    = (const float*)d_in[37];
    const float* na1_W    = (const float*)d_in[38];
    const float* na1_b    = (const float*)d_in[39];
    const float* la_W     = (const float*)d_in[40];
    const float* la_b     = (const float*)d_in[41];

    bf16*  kv       = (bf16*)d_ws;
    float* src_last = (float*)((char*)d_ws + (size_t)NTOK * 128 * sizeof(bf16));

    k_token<<<NTOK/64, 64, 0, stream>>>(X, emb_act, emb_zone, lin0_W, lin0_b,
        gat_W, gat_b, gat_a, gl0_W, gl0_b, gl1_W, gl1_b, gl2_W, gl2_b,
        Wqkv, bqkv, kv, src_last);

    k_head<<<B_, 128, 0, stream>>>(kv, src_last, Wqkv, bqkv, Wo, bo,
        ln1_g, ln1_b, W1, b1, W2, b2, ln2_g, ln2_b, relu_W, relu_b,
        nd_W, nd_b, ldt_W, ldt_b, nz_W, nz_b, lz_W, lz_b,
        na0_W, na0_b, na1_W, na1_b, la_W, la_b, (float*)d_out);
}

// Round 2
// 254.393 us; speedup vs baseline: 1.4644x; 1.4644x over previous
//
#include <hip/hip_runtime.h>
#include <hip/hip_bf16.h>

typedef __hip_bfloat16 bf16;

#define B_    2048
#define S_    40
#define NTOK  (B_*S_)
#define TPB   256
#define TOKB  64          // tokens per block
#define TSTRIDE 203       // dwords per token LDS region (odd -> bank-friendly)

// per-token region offsets (dwords)
#define OFF_FF   0        // 66 u32: 22 rows x 3 (bf16 pairs), later overwritten by hp
#define OFF_ACT0 66       // 64 f32 (pre0relu, then src)
#define OFF_ACT1 130      // 64 f32 (pre1relu)
#define OFF_HEAD 194      // 8 f32 (X cols 0..7)
#define OFF_PE   202      // 1 f32

__device__ inline unsigned pk2(float a, float b){
    __hip_bfloat16 ha = __float2bfloat16(a), hb = __float2bfloat16(b);
    unsigned short ua = *reinterpret_cast<unsigned short*>(&ha);
    unsigned short ub = *reinterpret_cast<unsigned short*>(&hb);
    return (unsigned)ua | ((unsigned)ub << 16);
}
__device__ inline float blo(unsigned u){ return __uint_as_float(u << 16); }
__device__ inline float bhi(unsigned u){ return __uint_as_float(u & 0xffff0000u); }

// ---------------- Kernel 1: 4 waves cooperate on 64 tokens ----------------
__global__ __launch_bounds__(TPB) void k_token(
    const float* __restrict__ X,
    const float* __restrict__ emb_act,
    const float* __restrict__ emb_zone,
    const float* __restrict__ lin0_W, const float* __restrict__ lin0_b,
    const float* __restrict__ gat_W,  const float* __restrict__ gat_b,
    const float* __restrict__ gat_a,
    const float* __restrict__ gl0_W,  const float* __restrict__ gl0_b,
    const float* __restrict__ gl1_W,  const float* __restrict__ gl1_b,
    const float* __restrict__ gl2_W,  const float* __restrict__ gl2_b,
    const float* __restrict__ Wqkv,   const float* __restrict__ bqkv,
    bf16* __restrict__ kv, float* __restrict__ src_last)
{
    __shared__ unsigned L[TOKB * TSTRIDE];   // 51968 B

    const int t    = threadIdx.x;
    const int w    = t >> 6;      // wave id 0..3
    const int lane = t & 63;      // token-local id in compute phases
    const int blk0 = blockIdx.x * TOKB;

    // ---------- phase 0: load X -> LDS (ff as bf16 rows, head as f32, pe) ----------
    for (int task = t; task < TOKB * 22; task += TPB){
        int tt = task / 22;
        int r  = task - tt * 22;
        const float* xp = X + (size_t)(blk0 + tt) * 118 + 8 + r * 5;
        float f0 = xp[0], f1 = xp[1], f2 = xp[2], f3 = xp[3], f4 = xp[4];
        unsigned* dst = &L[tt * TSTRIDE + OFF_FF + 3 * r];
        dst[0] = pk2(f0, f1); dst[1] = pk2(f2, f3); dst[2] = pk2(f4, 0.f);
    }
    if (t < TOKB){
        int tok = blk0 + t;
        const float2* xp = (const float2*)(X + (size_t)tok * 118);
        float* hd = (float*)&L[t * TSTRIDE + OFF_HEAD];
        #pragma unroll
        for (int p = 0; p < 4; ++p){ float2 v = xp[p]; hd[2*p] = v.x; hd[2*p+1] = v.y; }
        int b = tok / 40, s = tok - b * 40;
        float denom = powf(100.0f, (2.0f * (float)s) / 40.0f);
        float ang   = (float)b / denom;
        float pe    = ((s & 1) == 0) ? sinf(ang) : cosf(ang);
        ((float*)&L[t * TSTRIDE + OFF_PE])[0] = pe;
    }
    __syncthreads();

    const unsigned tb = lane * TSTRIDE;

    // ---------- phase 1: GAT (wave w owns i-nodes wbase..wbase+nI-1) ----------
    float va1[5], va2[5];
    float c1 = 0.f, c2 = 0.f;
    #pragma unroll
    for (int e = 0; e < 5; ++e){
        float u1 = 0.f, u2 = 0.f;
        #pragma unroll
        for (int d = 0; d < 5; ++d){
            u1 += gat_W[e*5+d] * gat_a[d];
            u2 += gat_W[e*5+d] * gat_a[5+d];
        }
        va1[e] = u1; va2[e] = u2;
    }
    #pragma unroll
    for (int d = 0; d < 5; ++d){ c1 += gat_b[d]*gat_a[d]; c2 += gat_b[d]*gat_a[5+d]; }

    float s2[22];
    float m2 = -1e30f;
    #pragma unroll
    for (int j = 0; j < 22; ++j){
        unsigned u0 = L[tb + 3*j], u1 = L[tb + 3*j + 1], u2 = L[tb + 3*j + 2];
        float f0 = blo(u0), f1 = bhi(u0), f2 = blo(u1), f3 = bhi(u1), f4 = blo(u2);
        s2[j] = c2 + f0*va2[0] + f1*va2[1] + f2*va2[2] + f3*va2[3] + f4*va2[4];
        m2 = fmaxf(m2, s2[j]);
    }

    const int wbase = w * 6;
    const int nI = (w == 3) ? 4 : 6;

    float s1own[6], mi[6], Z[6], ffp[6][5];
    #pragma unroll
    for (int ii = 0; ii < 6; ++ii){
        if (ii < nI){
            int j = wbase + ii;
            unsigned u0 = L[tb + 3*j], u1 = L[tb + 3*j + 1], u2 = L[tb + 3*j + 2];
            float f0 = blo(u0), f1 = bhi(u0), f2 = blo(u1), f3 = bhi(u1), f4 = blo(u2);
            float s1 = c1 + f0*va1[0] + f1*va1[1] + f2*va1[2] + f3*va1[3] + f4*va1[4];
            s1own[ii] = s1;
            float em = s1 + m2;
            mi[ii] = fmaxf(em, 0.2f * em);
            Z[ii] = 0.f;
            #pragma unroll
            for (int e = 0; e < 5; ++e) ffp[ii][e] = 0.f;
        }
    }

    #pragma unroll
    for (int j = 0; j < 22; ++j){
        unsigned u0 = L[tb + 3*j], u1 = L[tb + 3*j + 1], u2 = L[tb + 3*j + 2];
        float f0 = blo(u0), f1 = bhi(u0), f2 = blo(u1), f3 = bhi(u1), f4 = blo(u2);
        #pragma unroll
        for (int ii = 0; ii < 6; ++ii){
            if (ii < nI){
                float e2 = s1own[ii] + s2[j];
                float l  = fmaxf(e2, 0.2f * e2);
                float wg = __expf(l - mi[ii]);
                Z[ii] += wg;
                ffp[ii][0] = fmaf(wg, f0, ffp[ii][0]);
                ffp[ii][1] = fmaf(wg, f1, ffp[ii][1]);
                ffp[ii][2] = fmaf(wg, f2, ffp[ii][2]);
                ffp[ii][3] = fmaf(wg, f3, ffp[ii][3]);
                ffp[ii][4] = fmaf(wg, f4, ffp[ii][4]);
            }
        }
    }

    unsigned hpk[6][3];
    #pragma unroll
    for (int ii = 0; ii < 6; ++ii){
        if (ii < nI){
            float rz = 1.f / Z[ii];
            float h[5];
            #pragma unroll
            for (int d = 0; d < 5; ++d){
                float u = 0.f;
                #pragma unroll
                for (int e = 0; e < 5; ++e) u += ffp[ii][e] * gat_W[e*5+d];
                h[d] = u * rz + gat_b[d];
            }
            hpk[ii][0] = pk2(h[0], h[1]);
            hpk[ii][1] = pk2(h[2], h[3]);
            hpk[ii][2] = pk2(h[4], 0.f);
        }
    }
    __syncthreads();   // everyone done reading ff
    #pragma unroll
    for (int ii = 0; ii < 6; ++ii){
        if (ii < nI){
            int i = wbase + ii;
            L[tb + 3*i + 0] = hpk[ii][0];
            L[tb + 3*i + 1] = hpk[ii][1];
            L[tb + 3*i + 2] = hpk[ii][2];
        }
    }
    __syncthreads();

    // ---------- phase 2: gl0 (110 -> 64), wave w computes cols w*16.. ----------
    {
        const int c0 = w * 16;
        float acc[16];
        #pragma unroll
        for (int c = 0; c < 16; ++c) acc[c] = gl0_b[c0 + c];
        #pragma unroll 2
        for (int i = 0; i < 22; ++i){
            unsigned u0 = L[tb + 3*i], u1 = L[tb + 3*i + 1], u2 = L[tb + 3*i + 2];
            float h0 = blo(u0), h1 = bhi(u0), h2 = blo(u1), h3 = bhi(u1), h4 = blo(u2);
            const float* w0 = &gl0_W[(5*i+0)*64 + c0];
            const float* w1 = &gl0_W[(5*i+1)*64 + c0];
            const float* w2 = &gl0_W[(5*i+2)*64 + c0];
            const float* w3 = &gl0_W[(5*i+3)*64 + c0];
            const float* w4 = &gl0_W[(5*i+4)*64 + c0];
            #pragma unroll
            for (int c = 0; c < 16; ++c){
                float a = acc[c];
                a = fmaf(h0, w0[c], a);
                a = fmaf(h1, w1[c], a);
                a = fmaf(h2, w2[c], a);
                a = fmaf(h3, w3[c], a);
                a = fmaf(h4, w4[c], a);
                acc[c] = a;
            }
        }
        float* a0 = (float*)&L[tb + OFF_ACT0];
        #pragma unroll
        for (int c = 0; c < 16; ++c) a0[c0 + c] = fmaxf(acc[c], 0.f);
    }
    __syncthreads();

    // ---------- phase 3: gl1 (64 -> 64) ----------
    {
        const int c0 = w * 16;
        float acc[16];
        #pragma unroll
        for (int c = 0; c < 16; ++c) acc[c] = gl1_b[c0 + c];
        const float* a0 = (const float*)&L[tb + OFF_ACT0];
        #pragma unroll 4
        for (int d = 0; d < 64; ++d){
            float f = a0[d];
            const float* wr = &gl1_W[d*64 + c0];
            #pragma unroll
            for (int c = 0; c < 16; ++c) acc[c] = fmaf(f, wr[c], acc[c]);
        }
        float* a1 = (float*)&L[tb + OFF_ACT1];
        #pragma unroll
        for (int c = 0; c < 16; ++c) a1[c0 + c] = fmaxf(acc[c], 0.f);
    }
    __syncthreads();

    // ---------- phase 4: gl2 (64 -> 16, 4 cols/wave) + build src into ACT0 ----------
    {
        const int g0 = w * 4;
        float acc[4];
        #pragma unroll
        for (int c = 0; c < 4; ++c) acc[c] = gl2_b[g0 + c];
        const float* a1 = (const float*)&L[tb + OFF_ACT1];
        #pragma unroll 4
        for (int d = 0; d < 64; ++d){
            float f = a1[d];
            const float* wr = &gl2_W[d*16 + g0];
            #pragma unroll
            for (int c = 0; c < 4; ++c) acc[c] = fmaf(f, wr[c], acc[c]);
        }
        float pe = ((const float*)&L[tb + OFF_PE])[0];
        float* sr = (float*)&L[tb + OFF_ACT0];
        #pragma unroll
        for (int c = 0; c < 4; ++c) sr[48 + g0 + c] = fmaxf(acc[c], 0.f) + pe;

        const float* hd = (const float*)&L[tb + OFF_HEAD];
        if (w == 0){
            int ia = (int)hd[0];
            const float4* ea = (const float4*)(emb_act + ia * 16);
            #pragma unroll
            for (int p = 0; p < 4; ++p){
                float4 v = ea[p];
                sr[4*p+0] = v.x + pe; sr[4*p+1] = v.y + pe;
                sr[4*p+2] = v.z + pe; sr[4*p+3] = v.w + pe;
            }
        } else if (w == 1){
            int iz = (int)hd[1];
            const float4* ez = (const float4*)(emb_zone + iz * 16);
            #pragma unroll
            for (int p = 0; p < 4; ++p){
                float4 v = ez[p];
                sr[16+4*p+0] = v.x + pe; sr[16+4*p+1] = v.y + pe;
                sr[16+4*p+2] = v.z + pe; sr[16+4*p+3] = v.w + pe;
            }
        } else if (w == 2){
            float od[16];
            #pragma unroll
            for (int c = 0; c < 16; ++c) od[c] = lin0_b[c];
            #pragma unroll
            for (int e = 0; e < 6; ++e){
                float f = hd[2 + e];
                #pragma unroll
                for (int c = 0; c < 16; ++c) od[c] = fmaf(f, lin0_W[e*16+c], od[c]);
            }
            #pragma unroll
            for (int c = 0; c < 16; ++c) sr[32 + c] = od[c] + pe;
        }
    }
    __syncthreads();

    // ---------- phase 5: K,V projection (32 cols/wave) + src_last ----------
    {
        const int c0 = 64 + w * 32;
        float acc[32];
        #pragma unroll
        for (int c = 0; c < 32; ++c) acc[c] = bqkv[c0 + c];
        const float* sr = (const float*)&L[tb + OFF_ACT0];
        #pragma unroll 2
        for (int d = 0; d < 64; ++d){
            float f = sr[d];
            const float* wr = &Wqkv[d*192 + c0];
            #pragma unroll
            for (int c = 0; c < 32; ++c) acc[c] = fmaf(f, wr[c], acc[c]);
        }
        uint4* dst = (uint4*)(kv + (size_t)(blk0 + lane) * 128 + w * 32);
        #pragma unroll
        for (int g = 0; g < 2; ++g){
            uint4 u;
            u.x = pk2(acc[16*g+ 0], acc[16*g+ 1]);
            u.y = pk2(acc[16*g+ 2], acc[16*g+ 3]);
            u.z = pk2(acc[16*g+ 4], acc[16*g+ 5]);
            u.w = pk2(acc[16*g+ 6], acc[16*g+ 7]);
            dst[2*g] = u;
            uint4 v;
            v.x = pk2(acc[16*g+ 8], acc[16*g+ 9]);
            v.y = pk2(acc[16*g+10], acc[16*g+11]);
            v.z = pk2(acc[16*g+12], acc[16*g+13]);
            v.w = pk2(acc[16*g+14], acc[16*g+15]);
            dst[2*g+1] = v;
        }
        if (w == 0){
            int tok = blk0 + lane;
            int b = tok / 40, s = tok - b * 40;
            if (s == 39){
                float* sl = src_last + b * 64;
                #pragma unroll
                for (int c = 0; c < 64; ++c) sl[c] = sr[c];
            }
        }
    }
}

// ---------------- Kernel 2: per-batch attention@last + FFN + heads ----------------
__global__ __launch_bounds__(128) void k_head(
    const bf16* __restrict__ kv, const float* __restrict__ src_last,
    const float* __restrict__ Wqkv, const float* __restrict__ bqkv,
    const float* __restrict__ Wo,   const float* __restrict__ bo,
    const float* __restrict__ ln1_g, const float* __restrict__ ln1_b,
    const float* __restrict__ W1,   const float* __restrict__ b1,
    const float* __restrict__ W2,   const float* __restrict__ b2,
    const float* __restrict__ ln2_g, const float* __restrict__ ln2_b,
    const float* __restrict__ relu_W, const float* __restrict__ relu_b,
    const float* __restrict__ nd_W, const float* __restrict__ nd_b,
    const float* __restrict__ ldt_W, const float* __restrict__ ldt_b,
    const float* __restrict__ nz_W, const float* __restrict__ nz_b,
    const float* __restrict__ lz_W, const float* __restrict__ lz_b,
    const float* __restrict__ na0_W, const float* __restrict__ na0_b,
    const float* __restrict__ na1_W, const float* __restrict__ na1_b,
    const float* __restrict__ la_W, const float* __restrict__ la_b,
    float* __restrict__ out)
{
    const int b = blockIdx.x, t = threadIdx.x;
    __shared__ float kb[40][64];
    __shared__ float vb[40][64];
    __shared__ float qs[64], xb[64], yb[64], f1[256];
    __shared__ float xrs[64], m65[65], mzs[20], fa1[85], fa2[85], redv[1];

    {
        const unsigned* kv32 = (const unsigned*)(kv + (size_t)b * 40 * 128);
        for (int idx = t; idx < 2560; idx += 128){
            unsigned u = kv32[idx];
            int j  = idx >> 6;
            int cp = (idx & 63) << 1;
            float lo = __uint_as_float(u << 16);
            float hi = __uint_as_float(u & 0xffff0000u);
            if (cp < 64){ kb[j][cp] = lo; kb[j][cp+1] = hi; }
            else        { vb[j][cp-64] = lo; vb[j][cp-63] = hi; }
        }
    }
    if (t < 64) xb[t] = src_last[b*64 + t];
    __syncthreads();

    if (t < 64){
        float a = bqkv[t];
        for (int d = 0; d < 64; ++d) a += xb[d]*Wqkv[d*192 + t];
        qs[t] = a * 0.35355339059327373f;
    }
    __syncthreads();

    float o_c = 0.f;
    if (t < 64){
        const int h = t >> 3;
        const float* qh = &qs[h*8];
        float sc[40];
        float m = -1e30f;
        #pragma unroll
        for (int j = 0; j < 40; ++j){
            float a = 0.f;
            #pragma unroll
            for (int d = 0; d < 8; ++d) a += qh[d]*kb[j][h*8+d];
            sc[j] = a; m = fmaxf(m, a);
        }
        float Z = 0.f, acc = 0.f;
        #pragma unroll
        for (int j = 0; j < 40; ++j){
            float w = __expf(sc[j] - m);
            Z += w; acc += w * vb[j][t];
        }
        o_c = acc / Z;
    }
    if (t < 64) yb[t] = o_c;
    __syncthreads();

    float x1 = 0.f;
    if (t < 64){
        float a = bo[t];
        for (int d = 0; d < 64; ++d) a += yb[d]*Wo[d*64+t];
        float v = xb[t] + a;
        float sum = v;
        #pragma unroll
        for (int off = 1; off < 64; off <<= 1) sum += __shfl_xor(sum, off, 64);
        float mean = sum * (1.f/64.f);
        float dd = v - mean;
        float s2 = dd*dd;
        #pragma unroll
        for (int off = 1; off < 64; off <<= 1) s2 += __shfl_xor(s2, off, 64);
        float var = s2 * (1.f/64.f);
        x1 = dd * rsqrtf(var + 1e-5f) * ln1_g[t] + ln1_b[t];
    }
    __syncthreads();
    if (t < 64) xb[t] = x1;
    __syncthreads();

    for (int c = t; c < 256; c += 128){
        float a = b1[c];
        for (int d = 0; d < 64; ++d) a += xb[d]*W1[d*256+c];
        f1[c] = fmaxf(a, 0.f);
    }
    __syncthreads();

    if (t < 64){
        float a = b2[t];
        for (int j = 0; j < 256; ++j) a += f1[j]*W2[j*64+t];
        float v = xb[t] + a;
        float sum = v;
        #pragma unroll
        for (int off = 1; off < 64; off <<= 1) sum += __shfl_xor(sum, off, 64);
        float mean = sum * (1.f/64.f);
        float dd = v - mean;
        float s2 = dd*dd;
        #pragma unroll
        for (int off = 1; off < 64; off <<= 1) s2 += __shfl_xor(s2, off, 64);
        float var = s2 * (1.f/64.f);
        yb[t] = dd * rsqrtf(var + 1e-5f) * ln2_g[t] + ln2_b[t];
    }
    __syncthreads();

    if (t < 64){
        float a = relu_b[t];
        for (int d = 0; d < 64; ++d) a += yb[d]*relu_W[d*64+t];
        xrs[t] = a;
    }
    __syncthreads();

    if (t < 64){
        float a = nd_b[t];
        for (int d = 0; d < 64; ++d) a += xrs[d]*nd_W[d*64+t];
        float contrib = a * ldt_W[t];
        #pragma unroll
        for (int off = 1; off < 64; off <<= 1) contrib += __shfl_xor(contrib, off, 64);
        if (t == 0) redv[0] = contrib + ldt_b[0];
    }
    __syncthreads();
    float dT = redv[0];

    if (t < 65){
        float a = nz_b[t] + dT*nz_W[t];
        for (int d = 0; d < 64; ++d) a += xrs[d]*nz_W[(1+d)*65+t];
        m65[t] = a;
    }
    __syncthreads();

    if (t < 20){
        float a = lz_b[t];
        for (int d = 0; d < 65; ++d) a += m65[d]*lz_W[d*20+t];
        mzs[t] = a;
    }
    __syncthreads();

    if (t < 85){
        float a = na0_b[t];
        for (int d = 0; d < 20; ++d) a += mzs[d]*na0_W[d*85+t];
        a += dT*na0_W[20*85+t];
        for (int d = 0; d < 64; ++d) a += xrs[d]*na0_W[(21+d)*85+t];
        fa1[t] = a;
    }
    __syncthreads();
    if (t < 85){
        float a = na1_b[t];
        for (int d = 0; d < 85; ++d) a += fa1[d]*na1_W[d*85+t];
        fa2[t] = a;
    }
    __syncthreads();

    if (t == 0) out[b*26] = dT;
    if (t < 20) out[b*26 + 1 + t] = mzs[t];
    if (t < 5){
        float a = la_b[t];
        for (int d = 0; d < 85; ++d) a += fa2[d]*la_W[d*5+t];
        out[b*26 + 21 + t] = a;
    }
}

extern "C" void kernel_launch(void* const* d_in, const int* in_sizes, int n_in,
                              void* d_out, int out_size, void* d_ws, size_t ws_size,
                              hipStream_t stream)
{
    const float* X        = (const float*)d_in[0];
    const float* emb_act  = (const float*)d_in[1];
    const float* emb_zone = (const float*)d_in[2];
    const float* lin0_W   = (const float*)d_in[3];
    const float* lin0_b   = (const float*)d_in[4];
    const float* gat_W    = (const float*)d_in[5];
    const float* gat_b    = (const float*)d_in[6];
    const float* gat_a    = (const float*)d_in[7];
    const float* gl0_W    = (const float*)d_in[8];
    const float* gl0_b    = (const float*)d_in[9];
    const float* gl1_W    = (const float*)d_in[10];
    const float* gl1_b    = (const float*)d_in[11];
    const float* gl2_W    = (const float*)d_in[12];
    const float* gl2_b    = (const float*)d_in[13];
    const float* Wqkv     = (const float*)d_in[14];
    const float* bqkv     = (const float*)d_in[15];
    const float* Wo       = (const float*)d_in[16];
    const float* bo       = (const float*)d_in[17];
    const float* ln1_g    = (const float*)d_in[18];
    const float* ln1_b    = (const float*)d_in[19];
    const float* W1       = (const float*)d_in[20];
    const float* b1       = (const float*)d_in[21];
    const float* W2       = (const float*)d_in[22];
    const float* b2       = (const float*)d_in[23];
    const float* ln2_g    = (const float*)d_in[24];
    const float* ln2_b    = (const float*)d_in[25];
    const float* relu_W   = (const float*)d_in[26];
    const float* relu_b   = (const float*)d_in[27];
    const float* nd_W     = (const float*)d_in[28];
    const float* nd_b     = (const float*)d_in[29];
    const float* ldt_W    = (const float*)d_in[30];
    const float* ldt_b    = (const float*)d_in[31];
    const float* nz_W     = (const float*)d_in[32];
    const float* nz_b     = (const float*)d_in[33];
    const float* lz_W     = (const float*)d_in[34];
    const float* lz_b     = (const float*)d_in[35];
    const float* na0_W    = (const float*)d_in[36];
    const float* na0_b    = (const float*)d_in[37];
    const float* na1_W    = (const float*)d_in[38];
    const float* na1_b    = (const float*)d_in[39];
    const float* la_W     = (const float*)d_in[40];
    const float* la_b     = (const float*)d_in[41];

    bf16*  kv       = (bf16*)d_ws;
    float* src_last = (float*)((char*)d_ws + (size_t)NTOK * 128 * sizeof(bf16));

    k_token<<<NTOK/TOKB, TPB, 0, stream>>>(X, emb_act, emb_zone, lin0_W, lin0_b,
        gat_W, gat_b, gat_a, gl0_W, gl0_b, gl1_W, gl1_b, gl2_W, gl2_b,
        Wqkv, bqkv, kv, src_last);

    k_head<<<B_, 128, 0, stream>>>(kv, src_last, Wqkv, bqkv, Wo, bo,
        ln1_g, ln1_b, W1, b1, W2, b2, ln2_g, ln2_b, relu_W, relu_b,
        nd_W, nd_b, ldt_W, ldt_b, nz_W, nz_b, lz_W, lz_b,
        na0_W, na0_b, na1_W, na1_b, la_W, la_b, (float*)d_out);
}

// Round 3
// 157.509 us; speedup vs baseline: 2.3651x; 1.6151x over previous
//
#include <hip/hip_runtime.h>
#include <hip/hip_bf16.h>

typedef __hip_bfloat16 bf16;
typedef float f32x4 __attribute__((ext_vector_type(4)));
typedef short s16x8 __attribute__((ext_vector_type(8)));

#define B_    2048
#define S_    40
#define NTOK  (B_*S_)
#define TPB   256
#define TOKB  64

// LDS layout (dwords)
#define FF_OFF   0        // 64 tokens x 67 u32 (ff as bf16 pairs, stride 67 -> conflict-free)
#define A0_OFFD  4288     // A0: 64 rows x 384B (bf16 K=160 used, k=6i+d), 6144 dwords
#define A1_OFFD  10432    // A1: 64 rows x 128B (bf16 64 feats), 2048 dwords
#define HEAD_OFFD 12480   // 64 x 8 f32
#define PE_OFFD  12992    // 64 f32
#define LDS_DW   13056    // 52224 B -> 3 blocks/CU

#define A0B (A0_OFFD*4)
#define A1B (A1_OFFD*4)

__device__ inline unsigned pk2(float a, float b){
    __hip_bfloat16 ha = __float2bfloat16(a), hb = __float2bfloat16(b);
    unsigned short ua = *reinterpret_cast<unsigned short*>(&ha);
    unsigned short ub = *reinterpret_cast<unsigned short*>(&hb);
    return (unsigned)ua | ((unsigned)ub << 16);
}
__device__ inline float blo(unsigned u){ return __uint_as_float(u << 16); }
__device__ inline float bhi(unsigned u){ return __uint_as_float(u & 0xffff0000u); }

__device__ inline f32x4 MFMA(uint4 a, uint4 b, f32x4 c){
    union { uint4 q; s16x8 s; } A, Bv;
    A.q = a; Bv.q = b;
    return __builtin_amdgcn_mfma_f32_16x16x32_bf16(A.s, Bv.s, c, 0, 0, 0);
}

// ---------------- Kernel 1: MFMA featurizer ----------------
__global__ __launch_bounds__(TPB) void k_token(
    const float* __restrict__ X,
    const float* __restrict__ emb_act,
    const float* __restrict__ emb_zone,
    const float* __restrict__ lin0_W, const float* __restrict__ lin0_b,
    const float* __restrict__ gat_W,  const float* __restrict__ gat_b,
    const float* __restrict__ gat_a,
    const float* __restrict__ gl0_W,  const float* __restrict__ gl0_b,
    const float* __restrict__ gl1_W,  const float* __restrict__ gl1_b,
    const float* __restrict__ gl2_W,  const float* __restrict__ gl2_b,
    const float* __restrict__ Wqkv,   const float* __restrict__ bqkv,
    bf16* __restrict__ kv, float* __restrict__ src_last)
{
    __shared__ unsigned L[LDS_DW];
    char* Lb = (char*)L;

    const int t    = threadIdx.x;
    const int w    = t >> 6;      // wave id 0..3
    const int lane = t & 63;
    const int half = (lane >> 4); // 0..3
    const int c15  = lane & 15;
    const int blk0 = blockIdx.x * TOKB;
    const int swzc = (c15 & 7) << 4;   // swizzle for frag reads (row = *16 + c15)

    // ---------- phase 0: X -> LDS ----------
    for (int task = t; task < TOKB * 22; task += TPB){
        int tt = task / 22;
        int r  = task - tt * 22;
        const float* xp = X + (size_t)(blk0 + tt) * 118 + 8 + r * 5;
        float f0 = xp[0], f1 = xp[1], f2 = xp[2], f3 = xp[3], f4 = xp[4];
        unsigned* dst = &L[FF_OFF + tt * 67 + 3 * r];
        dst[0] = pk2(f0, f1); dst[1] = pk2(f2, f3); dst[2] = pk2(f4, 0.f);
    }
    if (t < TOKB){
        int tok = blk0 + t;
        const float2* xp = (const float2*)(X + (size_t)tok * 118);
        float* hd = (float*)&L[HEAD_OFFD + t * 8];
        #pragma unroll
        for (int p = 0; p < 4; ++p){ float2 v = xp[p]; hd[2*p] = v.x; hd[2*p+1] = v.y; }
        int b = tok / 40, s = tok - b * 40;
        float denom = powf(100.0f, (2.0f * (float)s) / 40.0f);
        float ang   = (float)b / denom;
        float pe    = ((s & 1) == 0) ? sinf(ang) : cosf(ang);
        ((float*)&L[PE_OFFD])[t] = pe;
    }
    // zero-fill A0 pad region k in [132,160)
    for (int idx = t; idx < 64 * 14; idx += TPB){
        int row = idx / 14, p = idx - row * 14;
        int off = (264 + 4 * p) ^ ((row & 7) << 4);
        *(unsigned*)(Lb + A0B + row * 384 + off) = 0u;
    }
    __syncthreads();

    // ---------- phase 1: GAT -> hp (bf16) into A0 (k = 6i+d) ----------
    {
        const unsigned tb = FF_OFF + lane * 67;
        float va1[5], va2[5];
        float cc1 = 0.f, cc2 = 0.f;
        #pragma unroll
        for (int e = 0; e < 5; ++e){
            float u1 = 0.f, u2 = 0.f;
            #pragma unroll
            for (int d = 0; d < 5; ++d){
                u1 += gat_W[e*5+d] * gat_a[d];
                u2 += gat_W[e*5+d] * gat_a[5+d];
            }
            va1[e] = u1; va2[e] = u2;
        }
        #pragma unroll
        for (int d = 0; d < 5; ++d){ cc1 += gat_b[d]*gat_a[d]; cc2 += gat_b[d]*gat_a[5+d]; }

        float s2v[22];
        float m2 = -1e30f;
        #pragma unroll
        for (int j = 0; j < 22; ++j){
            unsigned u0 = L[tb + 3*j], u1 = L[tb + 3*j + 1], u2 = L[tb + 3*j + 2];
            float f0 = blo(u0), f1 = bhi(u0), f2 = blo(u1), f3 = bhi(u1), f4 = blo(u2);
            s2v[j] = cc2 + f0*va2[0] + f1*va2[1] + f2*va2[2] + f3*va2[3] + f4*va2[4];
            m2 = fmaxf(m2, s2v[j]);
        }

        const int wbase = w * 6;
        const int nI = (w == 3) ? 4 : 6;

        float s1own[6], mi[6], Z[6], ffp[6][5];
        #pragma unroll
        for (int ii = 0; ii < 6; ++ii){
            if (ii < nI){
                int j = wbase + ii;
                unsigned u0 = L[tb + 3*j], u1 = L[tb + 3*j + 1], u2 = L[tb + 3*j + 2];
                float f0 = blo(u0), f1 = bhi(u0), f2 = blo(u1), f3 = bhi(u1), f4 = blo(u2);
                float s1 = cc1 + f0*va1[0] + f1*va1[1] + f2*va1[2] + f3*va1[3] + f4*va1[4];
                s1own[ii] = s1;
                float em = s1 + m2;
                mi[ii] = fmaxf(em, 0.2f * em);
                Z[ii] = 0.f;
                #pragma unroll
                for (int e = 0; e < 5; ++e) ffp[ii][e] = 0.f;
            }
        }

        #pragma unroll
        for (int j = 0; j < 22; ++j){
            unsigned u0 = L[tb + 3*j], u1 = L[tb + 3*j + 1], u2 = L[tb + 3*j + 2];
            float f0 = blo(u0), f1 = bhi(u0), f2 = blo(u1), f3 = bhi(u1), f4 = blo(u2);
            #pragma unroll
            for (int ii = 0; ii < 6; ++ii){
                if (ii < nI){
                    float e2 = s1own[ii] + s2v[j];
                    float lr = fmaxf(e2, 0.2f * e2);
                    float wg = __expf(lr - mi[ii]);
                    Z[ii] += wg;
                    ffp[ii][0] = fmaf(wg, f0, ffp[ii][0]);
                    ffp[ii][1] = fmaf(wg, f1, ffp[ii][1]);
                    ffp[ii][2] = fmaf(wg, f2, ffp[ii][2]);
                    ffp[ii][3] = fmaf(wg, f3, ffp[ii][3]);
                    ffp[ii][4] = fmaf(wg, f4, ffp[ii][4]);
                }
            }
        }

        const int rswz = (lane & 7) << 4;
        #pragma unroll
        for (int ii = 0; ii < 6; ++ii){
            if (ii < nI){
                int i = wbase + ii;
                float rz = 1.f / Z[ii];
                float h[5];
                #pragma unroll
                for (int d = 0; d < 5; ++d){
                    float u = 0.f;
                    #pragma unroll
                    for (int e = 0; e < 5; ++e) u += ffp[ii][e] * gat_W[e*5+d];
                    h[d] = u * rz + gat_b[d];
                }
                int base = 12 * i;
                *(unsigned*)(Lb + A0B + lane*384 + ((base    ) ^ rswz)) = pk2(h[0], h[1]);
                *(unsigned*)(Lb + A0B + lane*384 + ((base + 4) ^ rswz)) = pk2(h[2], h[3]);
                *(unsigned*)(Lb + A0B + lane*384 + ((base + 8) ^ rswz)) = pk2(h[4], 0.f);
            }
        }
    }
    __syncthreads();

    // ---------- phase 2: gl0 MFMA (K=160, k=6i+d), wave w -> cols 16w.. ----------
    {
        const int col = w * 16 + c15;
        uint4 bf[5];
        #pragma unroll
        for (int S = 0; S < 5; ++S){
            unsigned pr[4];
            #pragma unroll
            for (int jj = 0; jj < 4; ++jj){
                int k0 = S*32 + half*8 + 2*jj;
                int i0 = k0 / 6, d0 = k0 - 6*i0;
                int k1 = k0 + 1;
                int i1 = k1 / 6, d1 = k1 - 6*i1;
                float v0 = (d0 < 5 && i0 < 22) ? gl0_W[(5*i0+d0)*64 + col] : 0.f;
                float v1 = (d1 < 5 && i1 < 22) ? gl0_W[(5*i1+d1)*64 + col] : 0.f;
                pr[jj] = pk2(v0, v1);
            }
            bf[S].x = pr[0]; bf[S].y = pr[1]; bf[S].z = pr[2]; bf[S].w = pr[3];
        }
        float bias = gl0_b[col];
        f32x4 ac0 = {bias,bias,bias,bias}, ac1 = ac0, ac2 = ac0, ac3 = ac0;
        #pragma unroll
        for (int S = 0; S < 5; ++S){
            int koff = S*64 + half*16;
            uint4 a0 = *(const uint4*)(Lb + A0B + (0*16 + c15)*384 + (koff ^ swzc));
            uint4 a1 = *(const uint4*)(Lb + A0B + (1*16 + c15)*384 + (koff ^ swzc));
            uint4 a2 = *(const uint4*)(Lb + A0B + (2*16 + c15)*384 + (koff ^ swzc));
            uint4 a3 = *(const uint4*)(Lb + A0B + (3*16 + c15)*384 + (koff ^ swzc));
            ac0 = MFMA(a0, bf[S], ac0);
            ac1 = MFMA(a1, bf[S], ac1);
            ac2 = MFMA(a2, bf[S], ac2);
            ac3 = MFMA(a3, bf[S], ac3);
        }
        const int off = col * 2;
        #pragma unroll
        for (int r = 0; r < 4; ++r){
            int row0 = 0*16 + half*4 + r;
            int row1 = 1*16 + half*4 + r;
            int row2 = 2*16 + half*4 + r;
            int row3 = 3*16 + half*4 + r;
            *(bf16*)(Lb + A1B + row0*128 + (off ^ ((row0 & 7) << 4))) = __float2bfloat16(fmaxf(ac0[r], 0.f));
            *(bf16*)(Lb + A1B + row1*128 + (off ^ ((row1 & 7) << 4))) = __float2bfloat16(fmaxf(ac1[r], 0.f));
            *(bf16*)(Lb + A1B + row2*128 + (off ^ ((row2 & 7) << 4))) = __float2bfloat16(fmaxf(ac2[r], 0.f));
            *(bf16*)(Lb + A1B + row3*128 + (off ^ ((row3 & 7) << 4))) = __float2bfloat16(fmaxf(ac3[r], 0.f));
        }
    }
    __syncthreads();

    // ---------- phase 3: gl1 MFMA (A1 -> A2 @ A0 region) ----------
    {
        const int col = w * 16 + c15;
        uint4 bf[2];
        #pragma unroll
        for (int S = 0; S < 2; ++S){
            unsigned pr[4];
            #pragma unroll
            for (int jj = 0; jj < 4; ++jj){
                int k0 = S*32 + half*8 + 2*jj;
                pr[jj] = pk2(gl1_W[k0*64 + col], gl1_W[(k0+1)*64 + col]);
            }
            bf[S].x = pr[0]; bf[S].y = pr[1]; bf[S].z = pr[2]; bf[S].w = pr[3];
        }
        float bias = gl1_b[col];
        f32x4 ac0 = {bias,bias,bias,bias}, ac1 = ac0, ac2 = ac0, ac3 = ac0;
        #pragma unroll
        for (int S = 0; S < 2; ++S){
            int koff = S*64 + half*16;
            uint4 a0 = *(const uint4*)(Lb + A1B + (0*16 + c15)*128 + (koff ^ swzc));
            uint4 a1 = *(const uint4*)(Lb + A1B + (1*16 + c15)*128 + (koff ^ swzc));
            uint4 a2 = *(const uint4*)(Lb + A1B + (2*16 + c15)*128 + (koff ^ swzc));
            uint4 a3 = *(const uint4*)(Lb + A1B + (3*16 + c15)*128 + (koff ^ swzc));
            ac0 = MFMA(a0, bf[S], ac0);
            ac1 = MFMA(a1, bf[S], ac1);
            ac2 = MFMA(a2, bf[S], ac2);
            ac3 = MFMA(a3, bf[S], ac3);
        }
        const int off = col * 2;
        #pragma unroll
        for (int r = 0; r < 4; ++r){
            int row0 = 0*16 + half*4 + r;
            int row1 = 1*16 + half*4 + r;
            int row2 = 2*16 + half*4 + r;
            int row3 = 3*16 + half*4 + r;
            *(bf16*)(Lb + A0B + row0*128 + (off ^ ((row0 & 7) << 4))) = __float2bfloat16(fmaxf(ac0[r], 0.f));
            *(bf16*)(Lb + A0B + row1*128 + (off ^ ((row1 & 7) << 4))) = __float2bfloat16(fmaxf(ac1[r], 0.f));
            *(bf16*)(Lb + A0B + row2*128 + (off ^ ((row2 & 7) << 4))) = __float2bfloat16(fmaxf(ac2[r], 0.f));
            *(bf16*)(Lb + A0B + row3*128 + (off ^ ((row3 & 7) << 4))) = __float2bfloat16(fmaxf(ac3[r], 0.f));
        }
    }
    __syncthreads();

    // ---------- phase 4: gl2 MFMA (wave w -> rowblk w) + src build into A3 @ A1 ----------
    {
        uint4 bf[2];
        #pragma unroll
        for (int S = 0; S < 2; ++S){
            unsigned pr[4];
            #pragma unroll
            for (int jj = 0; jj < 4; ++jj){
                int k0 = S*32 + half*8 + 2*jj;
                pr[jj] = pk2(gl2_W[k0*16 + c15], gl2_W[(k0+1)*16 + c15]);
            }
            bf[S].x = pr[0]; bf[S].y = pr[1]; bf[S].z = pr[2]; bf[S].w = pr[3];
        }
        float bias = gl2_b[c15];
        f32x4 ac = {bias,bias,bias,bias};
        #pragma unroll
        for (int S = 0; S < 2; ++S){
            int koff = S*64 + half*16;
            uint4 a = *(const uint4*)(Lb + A0B + (w*16 + c15)*128 + (koff ^ swzc));
            ac = MFMA(a, bf[S], ac);
        }
        const float* pef = (const float*)&L[PE_OFFD];
        const int off = (48 + c15) * 2;
        #pragma unroll
        for (int r = 0; r < 4; ++r){
            int row = w*16 + half*4 + r;
            float v = fmaxf(ac[r], 0.f) + pef[row];
            *(bf16*)(Lb + A1B + row*128 + (off ^ ((row & 7) << 4))) = __float2bfloat16(v);
        }

        // emb_act / emb_zone / od -> src cols 0..47
        const int tt = t & 63;
        const int wv = t >> 6;
        float pe = pef[tt];
        const float* hd = (const float*)&L[HEAD_OFFD + tt * 8];
        int ia = (int)hd[0], iz = (int)hd[1];
        const int tswz = (tt & 7) << 4;
        #pragma unroll
        for (int pp = 0; pp < 6; ++pp){
            int p = wv * 6 + pp;
            int c0 = 2 * p;
            float v0, v1;
            if (p < 8)        { v0 = emb_act[ia*16 + c0];        v1 = emb_act[ia*16 + c0 + 1]; }
            else if (p < 16)  { v0 = emb_zone[iz*16 + c0 - 16];  v1 = emb_zone[iz*16 + c0 - 15]; }
            else {
                int cc = c0 - 32;
                float o0 = lin0_b[cc], o1 = lin0_b[cc+1];
                #pragma unroll
                for (int e = 0; e < 6; ++e){
                    float f = hd[2 + e];
                    o0 = fmaf(f, lin0_W[e*16 + cc], o0);
                    o1 = fmaf(f, lin0_W[e*16 + cc + 1], o1);
                }
                v0 = o0; v1 = o1;
            }
            *(unsigned*)(Lb + A1B + tt*128 + ((4*p) ^ tswz)) = pk2(v0 + pe, v1 + pe);
        }
    }
    __syncthreads();

    // ---------- phase 5: src_last + KV MFMA ----------
    {
        int r0 = 39 - (blk0 % 40);
        if (t < 128){
            int tok = r0 + 40 * (t >> 6);
            if (tok < 64){
                int col = t & 63;
                bf16 hv = *(const bf16*)(Lb + A1B + tok*128 + ((col*2) ^ ((tok & 7) << 4)));
                src_last[(size_t)((blk0 + tok) / 40) * 64 + col] = __bfloat162float(hv);
            }
        }

        uint4 bfk[2][2];   // [cf][S]
        #pragma unroll
        for (int cf = 0; cf < 2; ++cf){
            int col = 64 + w*32 + cf*16 + c15;
            #pragma unroll
            for (int S = 0; S < 2; ++S){
                unsigned pr[4];
                #pragma unroll
                for (int jj = 0; jj < 4; ++jj){
                    int k0 = S*32 + half*8 + 2*jj;
                    pr[jj] = pk2(Wqkv[k0*192 + col], Wqkv[(k0+1)*192 + col]);
                }
                bfk[cf][S].x = pr[0]; bfk[cf][S].y = pr[1]; bfk[cf][S].z = pr[2]; bfk[cf][S].w = pr[3];
            }
        }
        float b0v = bqkv[64 + w*32 + c15];
        float b1v = bqkv[64 + w*32 + 16 + c15];
        f32x4 acc[4][2];
        #pragma unroll
        for (int R = 0; R < 4; ++R){
            acc[R][0] = (f32x4){b0v, b0v, b0v, b0v};
            acc[R][1] = (f32x4){b1v, b1v, b1v, b1v};
        }
        #pragma unroll
        for (int S = 0; S < 2; ++S){
            int koff = S*64 + half*16;
            #pragma unroll
            for (int R = 0; R < 4; ++R){
                uint4 a = *(const uint4*)(Lb + A1B + (R*16 + c15)*128 + (koff ^ swzc));
                acc[R][0] = MFMA(a, bfk[0][S], acc[R][0]);
                acc[R][1] = MFMA(a, bfk[1][S], acc[R][1]);
            }
        }
        // write KV tile [64][128] bf16, stride 256B, swizzled (reuse A0 region)
        #pragma unroll
        for (int R = 0; R < 4; ++R){
            #pragma unroll
            for (int cf = 0; cf < 2; ++cf){
                int lcol = w*32 + cf*16 + c15;
                int off = lcol * 2;
                #pragma unroll
                for (int r = 0; r < 4; ++r){
                    int row = R*16 + half*4 + r;
                    *(bf16*)(Lb + A0B + row*256 + (off ^ ((row & 7) << 4))) = __float2bfloat16(acc[R][cf][r]);
                }
            }
        }
    }
    __syncthreads();

    // coalesced KV store: thread -> 64B
    {
        int row = t >> 2;
        int q = t & 3;
        #pragma unroll
        for (int c = 0; c < 4; ++c){
            int chunk = q*4 + c;
            uint4 d = *(const uint4*)(Lb + A0B + row*256 + ((chunk*16) ^ ((row & 7) << 4)));
            *((uint4*)(kv + (size_t)(blk0 + row) * 128 + chunk * 8)) = d;
        }
    }
}

// ---------------- Kernel 2: per-batch attention@last + FFN + heads ----------------
__global__ __launch_bounds__(128) void k_head(
    const bf16* __restrict__ kv, const float* __restrict__ src_last,
    const float* __restrict__ Wqkv, const float* __restrict__ bqkv,
    const float* __restrict__ Wo,   const float* __restrict__ bo,
    const float* __restrict__ ln1_g, const float* __restrict__ ln1_b,
    const float* __restrict__ W1,   const float* __restrict__ b1,
    const float* __restrict__ W2,   const float* __restrict__ b2,
    const float* __restrict__ ln2_g, const float* __restrict__ ln2_b,
    const float* __restrict__ relu_W, const float* __restrict__ relu_b,
    const float* __restrict__ nd_W, const float* __restrict__ nd_b,
    const float* __restrict__ ldt_W, const float* __restrict__ ldt_b,
    const float* __restrict__ nz_W, const float* __restrict__ nz_b,
    const float* __restrict__ lz_W, const float* __restrict__ lz_b,
    const float* __restrict__ na0_W, const float* __restrict__ na0_b,
    const float* __restrict__ na1_W, const float* __restrict__ na1_b,
    const float* __restrict__ la_W, const float* __restrict__ la_b,
    float* __restrict__ out)
{
    const int b = blockIdx.x, t = threadIdx.x;
    __shared__ float kb[40][64];
    __shared__ float vb[40][64];
    __shared__ float qs[64], xb[64], yb[64], f1[256];
    __shared__ float xrs[64], m65[65], mzs[20], fa1[85], fa2[85], redv[1];

    {
        const unsigned* kv32 = (const unsigned*)(kv + (size_t)b * 40 * 128);
        for (int idx = t; idx < 2560; idx += 128){
            unsigned u = kv32[idx];
            int j  = idx >> 6;
            int cp = (idx & 63) << 1;
            float lo = __uint_as_float(u << 16);
            float hi = __uint_as_float(u & 0xffff0000u);
            if (cp < 64){ kb[j][cp] = lo; kb[j][cp+1] = hi; }
            else        { vb[j][cp-64] = lo; vb[j][cp-63] = hi; }
        }
    }
    if (t < 64) xb[t] = src_last[b*64 + t];
    __syncthreads();

    if (t < 64){
        float a = bqkv[t];
        for (int d = 0; d < 64; ++d) a += xb[d]*Wqkv[d*192 + t];
        qs[t] = a * 0.35355339059327373f;
    }
    __syncthreads();

    float o_c = 0.f;
    if (t < 64){
        const int h = t >> 3;
        const float* qh = &qs[h*8];
        float sc[40];
        float m = -1e30f;
        #pragma unroll
        for (int j = 0; j < 40; ++j){
            float a = 0.f;
            #pragma unroll
            for (int d = 0; d < 8; ++d) a += qh[d]*kb[j][h*8+d];
            sc[j] = a; m = fmaxf(m, a);
        }
        float Z = 0.f, acc = 0.f;
        #pragma unroll
        for (int j = 0; j < 40; ++j){
            float w = __expf(sc[j] - m);
            Z += w; acc += w * vb[j][t];
        }
        o_c = acc / Z;
    }
    if (t < 64) yb[t] = o_c;
    __syncthreads();

    float x1 = 0.f;
    if (t < 64){
        float a = bo[t];
        for (int d = 0; d < 64; ++d) a += yb[d]*Wo[d*64+t];
        float v = xb[t] + a;
        float sum = v;
        #pragma unroll
        for (int off = 1; off < 64; off <<= 1) sum += __shfl_xor(sum, off, 64);
        float mean = sum * (1.f/64.f);
        float dd = v - mean;
        float s2 = dd*dd;
        #pragma unroll
        for (int off = 1; off < 64; off <<= 1) s2 += __shfl_xor(s2, off, 64);
        float var = s2 * (1.f/64.f);
        x1 = dd * rsqrtf(var + 1e-5f) * ln1_g[t] + ln1_b[t];
    }
    __syncthreads();
    if (t < 64) xb[t] = x1;
    __syncthreads();

    for (int c = t; c < 256; c += 128){
        float a = b1[c];
        for (int d = 0; d < 64; ++d) a += xb[d]*W1[d*256+c];
        f1[c] = fmaxf(a, 0.f);
    }
    __syncthreads();

    if (t < 64){
        float a = b2[t];
        for (int j = 0; j < 256; ++j) a += f1[j]*W2[j*64+t];
        float v = xb[t] + a;
        float sum = v;
        #pragma unroll
        for (int off = 1; off < 64; off <<= 1) sum += __shfl_xor(sum, off, 64);
        float mean = sum * (1.f/64.f);
        float dd = v - mean;
        float s2 = dd*dd;
        #pragma unroll
        for (int off = 1; off < 64; off <<= 1) s2 += __shfl_xor(s2, off, 64);
        float var = s2 * (1.f/64.f);
        yb[t] = dd * rsqrtf(var + 1e-5f) * ln2_g[t] + ln2_b[t];
    }
    __syncthreads();

    if (t < 64){
        float a = relu_b[t];
        for (int d = 0; d < 64; ++d) a += yb[d]*relu_W[d*64+t];
        xrs[t] = a;
    }
    __syncthreads();

    if (t < 64){
        float a = nd_b[t];
        for (int d = 0; d < 64; ++d) a += xrs[d]*nd_W[d*64+t];
        float contrib = a * ldt_W[t];
        #pragma unroll
        for (int off = 1; off < 64; off <<= 1) contrib += __shfl_xor(contrib, off, 64);
        if (t == 0) redv[0] = contrib + ldt_b[0];
    }
    __syncthreads();
    float dT = redv[0];

    if (t < 65){
        float a = nz_b[t] + dT*nz_W[t];
        for (int d = 0; d < 64; ++d) a += xrs[d]*nz_W[(1+d)*65+t];
        m65[t] = a;
    }
    __syncthreads();

    if (t < 20){
        float a = lz_b[t];
        for (int d = 0; d < 65; ++d) a += m65[d]*lz_W[d*20+t];
        mzs[t] = a;
    }
    __syncthreads();

    if (t < 85){
        float a = na0_b[t];
        for (int d = 0; d < 20; ++d) a += mzs[d]*na0_W[d*85+t];
        a += dT*na0_W[20*85+t];
        for (int d = 0; d < 64; ++d) a += xrs[d]*na0_W[(21+d)*85+t];
        fa1[t] = a;
    }
    __syncthreads();
    if (t < 85){
        float a = na1_b[t];
        for (int d = 0; d < 85; ++d) a += fa1[d]*na1_W[d*85+t];
        fa2[t] = a;
    }
    __syncthreads();

    if (t == 0) out[b*26] = dT;
    if (t < 20) out[b*26 + 1 + t] = mzs[t];
    if (t < 5){
        float a = la_b[t];
        for (int d = 0; d < 85; ++d) a += fa2[d]*la_W[d*5+t];
        out[b*26 + 21 + t] = a;
    }
}

extern "C" void kernel_launch(void* const* d_in, const int* in_sizes, int n_in,
                              void* d_out, int out_size, void* d_ws, size_t ws_size,
                              hipStream_t stream)
{
    const float* X        = (const float*)d_in[0];
    const float* emb_act  = (const float*)d_in[1];
    const float* emb_zone = (const float*)d_in[2];
    const float* lin0_W   = (const float*)d_in[3];
    const float* lin0_b   = (const float*)d_in[4];
    const float* gat_W    = (const float*)d_in[5];
    const float* gat_b    = (const float*)d_in[6];
    const float* gat_a    = (const float*)d_in[7];
    const float* gl0_W    = (const float*)d_in[8];
    const float* gl0_b    = (const float*)d_in[9];
    const float* gl1_W    = (const float*)d_in[10];
    const float* gl1_b    = (const float*)d_in[11];
    const float* gl2_W    = (const float*)d_in[12];
    const float* gl2_b    = (const float*)d_in[13];
    const float* Wqkv     = (const float*)d_in[14];
    const float* bqkv     = (const float*)d_in[15];
    const float* Wo       = (const float*)d_in[16];
    const float* bo       = (const float*)d_in[17];
    const float* ln1_g    = (const float*)d_in[18];
    const float* ln1_b    = (const float*)d_in[19];
    const float* W1       = (const float*)d_in[20];
    const float* b1       = (const float*)d_in[21];
    const float* W2       = (const float*)d_in[22];
    const float* b2       = (const float*)d_in[23];
    const float* ln2_g    = (const float*)d_in[24];
    const float* ln2_b    = (const float*)d_in[25];
    const float* relu_W   = (const float*)d_in[26];
    const float* relu_b   = (const float*)d_in[27];
    const float* nd_W     = (const float*)d_in[28];
    const float* nd_b     = (const float*)d_in[29];
    const float* ldt_W    = (const float*)d_in[30];
    const float* ldt_b    = (const float*)d_in[31];
    const float* nz_W     = (const float*)d_in[32];
    const float* nz_b     = (const float*)d_in[33];
    const float* lz_W     = (const float*)d_in[34];
    const float* lz_b     = (const float*)d_in[35];
    const float* na0_W    = (const float*)d_in[36];
    const float* na0_b    = (const float*)d_in[37];
    const float* na1_W    = (const float*)d_in[38];
    const float* na1_b    = (const float*)d_in[39];
    const float* la_W     = (const float*)d_in[40];
    const float* la_b     = (const float*)d_in[41];

    bf16*  kv       = (bf16*)d_ws;
    float* src_last = (float*)((char*)d_ws + (size_t)NTOK * 128 * sizeof(bf16));

    k_token<<<NTOK/TOKB, TPB, 0, stream>>>(X, emb_act, emb_zone, lin0_W, lin0_b,
        gat_W, gat_b, gat_a, gl0_W, gl0_b, gl1_W, gl1_b, gl2_W, gl2_b,
        Wqkv, bqkv, kv, src_last);

    k_head<<<B_, 128, 0, stream>>>(kv, src_last, Wqkv, bqkv, Wo, bo,
        ln1_g, ln1_b, W1, b1, W2, b2, ln2_g, ln2_b, relu_W, relu_b,
        nd_W, nd_b, ldt_W, ldt_b, nz_W, nz_b, lz_W, lz_b,
        na0_W, na0_b, na1_W, na1_b, la_W, la_b, (float*)d_out);
}

// Round 4
// 133.977 us; speedup vs baseline: 2.7805x; 1.1756x over previous
//
#include <hip/hip_runtime.h>
#include <hip/hip_bf16.h>

typedef __hip_bfloat16 bf16;
typedef float f32x4 __attribute__((ext_vector_type(4)));
typedef short s16x8 __attribute__((ext_vector_type(8)));

#define B_    2048
#define S_    40
#define NTOK  (B_*S_)
#define TPB   256
#define TOKB  64

// LDS layout (dwords). A1 aliases the FF region (FF dead after phase 1).
#define FF_OFF    0       // 64 tokens x 67 u32 (ff bf16 pairs)
#define A1_OFFD   0       // A1: 64 rows x 128B bf16 (aliases FF)
#define A0_OFFD   4288    // A0: 64 rows x 384B bf16 (K=160), also KV staging 64x256B
#define HEAD_OFFD 10432   // 64 x 8 f32
#define PE_OFFD   10944   // 64 f32
#define LDS_DW    11008   // 44032 B

#define A0B (A0_OFFD*4)
#define A1B (A1_OFFD*4)

// packW fragment offsets (uint4 units)
#define PK_GL0 0          // [w][S=5][lane]  -> 1280
#define PK_GL1 1280       // [w][S=2][lane]  -> 512
#define PK_GL2 1792       // [S=2][lane]     -> 128
#define PK_KV  1920       // [w][cf=2][S=2][lane] -> 1024
#define PK_TOT 2944

__device__ inline unsigned pk2(float a, float b){
    __hip_bfloat16 ha = __float2bfloat16(a), hb = __float2bfloat16(b);
    unsigned short ua = *reinterpret_cast<unsigned short*>(&ha);
    unsigned short ub = *reinterpret_cast<unsigned short*>(&hb);
    return (unsigned)ua | ((unsigned)ub << 16);
}
__device__ inline float blo(unsigned u){ return __uint_as_float(u << 16); }
__device__ inline float bhi(unsigned u){ return __uint_as_float(u & 0xffff0000u); }

__device__ inline f32x4 MFMA(uint4 a, uint4 b, f32x4 c){
    union { uint4 q; s16x8 s; } A, Bv;
    A.q = a; Bv.q = b;
    return __builtin_amdgcn_mfma_f32_16x16x32_bf16(A.s, Bv.s, c, 0, 0, 0);
}

// ---------------- Kernel 0: pre-pack weight fragments ----------------
__global__ __launch_bounds__(256) void k_pack(
    const float* __restrict__ gl0_W, const float* __restrict__ gl1_W,
    const float* __restrict__ gl2_W, const float* __restrict__ Wqkv,
    uint4* __restrict__ packW)
{
    int f = blockIdx.x * 256 + threadIdx.x;
    if (f >= PK_TOT) return;
    unsigned pr[4];
    if (f < PK_GL1){
        int w = f / 320, r = f % 320, S = r / 64, lane = r % 64;
        int half = lane >> 4, c15 = lane & 15, col = w * 16 + c15;
        #pragma unroll
        for (int jj = 0; jj < 4; ++jj){
            int k0 = S*32 + half*8 + 2*jj;
            int i0 = k0 / 6, d0 = k0 - 6*i0;
            int k1 = k0 + 1, i1 = k1 / 6, d1 = k1 - 6*i1;
            float v0 = (d0 < 5 && i0 < 22) ? gl0_W[(5*i0+d0)*64 + col] : 0.f;
            float v1 = (d1 < 5 && i1 < 22) ? gl0_W[(5*i1+d1)*64 + col] : 0.f;
            pr[jj] = pk2(v0, v1);
        }
    } else if (f < PK_GL2){
        int g = f - PK_GL1, w = g / 128, r = g % 128, S = r / 64, lane = r % 64;
        int half = lane >> 4, c15 = lane & 15, col = w * 16 + c15;
        #pragma unroll
        for (int jj = 0; jj < 4; ++jj){
            int k0 = S*32 + half*8 + 2*jj;
            pr[jj] = pk2(gl1_W[k0*64 + col], gl1_W[(k0+1)*64 + col]);
        }
    } else if (f < PK_KV){
        int g = f - PK_GL2, S = g / 64, lane = g % 64;
        int half = lane >> 4, c15 = lane & 15;
        #pragma unroll
        for (int jj = 0; jj < 4; ++jj){
            int k0 = S*32 + half*8 + 2*jj;
            pr[jj] = pk2(gl2_W[k0*16 + c15], gl2_W[(k0+1)*16 + c15]);
        }
    } else {
        int g = f - PK_KV, w = g / 256, r = g % 256, cf = r / 128, r2 = r % 128;
        int S = r2 / 64, lane = r2 % 64;
        int half = lane >> 4, c15 = lane & 15, col = 64 + w*32 + cf*16 + c15;
        #pragma unroll
        for (int jj = 0; jj < 4; ++jj){
            int k0 = S*32 + half*8 + 2*jj;
            pr[jj] = pk2(Wqkv[k0*192 + col], Wqkv[(k0+1)*192 + col]);
        }
    }
    packW[f] = (uint4){pr[0], pr[1], pr[2], pr[3]};
}

// ---------------- Kernel 1: MFMA featurizer ----------------
__global__ __launch_bounds__(TPB) void k_token(
    const float* __restrict__ X,
    const float* __restrict__ emb_act,
    const float* __restrict__ emb_zone,
    const float* __restrict__ lin0_W, const float* __restrict__ lin0_b,
    const float* __restrict__ gat_W,  const float* __restrict__ gat_b,
    const float* __restrict__ gat_a,
    const float* __restrict__ gl0_b,  const float* __restrict__ gl1_b,
    const float* __restrict__ gl2_b,  const float* __restrict__ bqkv,
    const uint4* __restrict__ packW,
    bf16* __restrict__ kv, float* __restrict__ src_last)
{
    __shared__ unsigned L[LDS_DW];
    char* Lb = (char*)L;

    const int t    = threadIdx.x;
    const int w    = t >> 6;      // wave id 0..3
    const int lane = t & 63;
    const int half = (lane >> 4); // 0..3
    const int c15  = lane & 15;
    const int blk0 = blockIdx.x * TOKB;
    const int swzc = (c15 & 7) << 4;

    // ---------- phase 0: X -> LDS ----------
    for (int task = t; task < TOKB * 22; task += TPB){
        int tt = task / 22;
        int r  = task - tt * 22;
        const float* xp = X + (size_t)(blk0 + tt) * 118 + 8 + r * 5;
        float f0 = xp[0], f1 = xp[1], f2 = xp[2], f3 = xp[3], f4 = xp[4];
        unsigned* dst = &L[FF_OFF + tt * 67 + 3 * r];
        dst[0] = pk2(f0, f1); dst[1] = pk2(f2, f3); dst[2] = pk2(f4, 0.f);
    }
    if (t < TOKB){
        int tok = blk0 + t;
        const float2* xp = (const float2*)(X + (size_t)tok * 118);
        float* hd = (float*)&L[HEAD_OFFD + t * 8];
        #pragma unroll
        for (int p = 0; p < 4; ++p){ float2 v = xp[p]; hd[2*p] = v.x; hd[2*p+1] = v.y; }
        int b = tok / 40, s = tok - b * 40;
        float denom = powf(100.0f, (2.0f * (float)s) / 40.0f);
        float ang   = (float)b / denom;
        float pe    = ((s & 1) == 0) ? sinf(ang) : cosf(ang);
        ((float*)&L[PE_OFFD])[t] = pe;
    }
    // zero-fill A0 pad region k in [132,160) (avoid NaN garbage * 0)
    for (int idx = t; idx < 64 * 14; idx += TPB){
        int row = idx / 14, p = idx - row * 14;
        int off = (264 + 4 * p) ^ ((row & 7) << 4);
        *(unsigned*)(Lb + A0B + row * 384 + off) = 0u;
    }
    __syncthreads();

    // ---------- phase 1: GAT -> hp (bf16) into A0 (k = 6i+d) ----------
    {
        const unsigned tb = FF_OFF + lane * 67;
        float va1[5], va2[5];
        float cc1 = 0.f, cc2 = 0.f;
        #pragma unroll
        for (int e = 0; e < 5; ++e){
            float u1 = 0.f, u2 = 0.f;
            #pragma unroll
            for (int d = 0; d < 5; ++d){
                u1 += gat_W[e*5+d] * gat_a[d];
                u2 += gat_W[e*5+d] * gat_a[5+d];
            }
            va1[e] = u1; va2[e] = u2;
        }
        #pragma unroll
        for (int d = 0; d < 5; ++d){ cc1 += gat_b[d]*gat_a[d]; cc2 += gat_b[d]*gat_a[5+d]; }

        float s2v[22];
        float m2 = -1e30f;
        #pragma unroll
        for (int j = 0; j < 22; ++j){
            unsigned u0 = L[tb + 3*j], u1 = L[tb + 3*j + 1], u2 = L[tb + 3*j + 2];
            float f0 = blo(u0), f1 = bhi(u0), f2 = blo(u1), f3 = bhi(u1), f4 = blo(u2);
            s2v[j] = cc2 + f0*va2[0] + f1*va2[1] + f2*va2[2] + f3*va2[3] + f4*va2[4];
            m2 = fmaxf(m2, s2v[j]);
        }

        const int wbase = w * 6;
        const int nI = (w == 3) ? 4 : 6;

        float s1own[6], mi[6], Z[6], ffp[6][5];
        #pragma unroll
        for (int ii = 0; ii < 6; ++ii){
            if (ii < nI){
                int j = wbase + ii;
                unsigned u0 = L[tb + 3*j], u1 = L[tb + 3*j + 1], u2 = L[tb + 3*j + 2];
                float f0 = blo(u0), f1 = bhi(u0), f2 = blo(u1), f3 = bhi(u1), f4 = blo(u2);
                float s1 = cc1 + f0*va1[0] + f1*va1[1] + f2*va1[2] + f3*va1[3] + f4*va1[4];
                s1own[ii] = s1;
                float em = s1 + m2;
                mi[ii] = fmaxf(em, 0.2f * em);
                Z[ii] = 0.f;
                #pragma unroll
                for (int e = 0; e < 5; ++e) ffp[ii][e] = 0.f;
            }
        }

        #pragma unroll
        for (int j = 0; j < 22; ++j){
            unsigned u0 = L[tb + 3*j], u1 = L[tb + 3*j + 1], u2 = L[tb + 3*j + 2];
            float f0 = blo(u0), f1 = bhi(u0), f2 = blo(u1), f3 = bhi(u1), f4 = blo(u2);
            #pragma unroll
            for (int ii = 0; ii < 6; ++ii){
                if (ii < nI){
                    float e2 = s1own[ii] + s2v[j];
                    float lr = fmaxf(e2, 0.2f * e2);
                    float wg = __expf(lr - mi[ii]);
                    Z[ii] += wg;
                    ffp[ii][0] = fmaf(wg, f0, ffp[ii][0]);
                    ffp[ii][1] = fmaf(wg, f1, ffp[ii][1]);
                    ffp[ii][2] = fmaf(wg, f2, ffp[ii][2]);
                    ffp[ii][3] = fmaf(wg, f3, ffp[ii][3]);
                    ffp[ii][4] = fmaf(wg, f4, ffp[ii][4]);
                }
            }
        }

        const int rswz = (lane & 7) << 4;
        #pragma unroll
        for (int ii = 0; ii < 6; ++ii){
            if (ii < nI){
                int i = wbase + ii;
                float rz = 1.f / Z[ii];
                float h[5];
                #pragma unroll
                for (int d = 0; d < 5; ++d){
                    float u = 0.f;
                    #pragma unroll
                    for (int e = 0; e < 5; ++e) u += ffp[ii][e] * gat_W[e*5+d];
                    h[d] = u * rz + gat_b[d];
                }
                int base = 12 * i;
                *(unsigned*)(Lb + A0B + lane*384 + ((base    ) ^ rswz)) = pk2(h[0], h[1]);
                *(unsigned*)(Lb + A0B + lane*384 + ((base + 4) ^ rswz)) = pk2(h[2], h[3]);
                *(unsigned*)(Lb + A0B + lane*384 + ((base + 8) ^ rswz)) = pk2(h[4], 0.f);
            }
        }
    }
    __syncthreads();

    // ---------- phase 2: gl0 MFMA (K=160), wave w -> cols 16w.. ; out -> A1 ----------
    {
        uint4 bfr[5];
        #pragma unroll
        for (int S = 0; S < 5; ++S) bfr[S] = packW[PK_GL0 + (w*5 + S)*64 + lane];
        const int col = w * 16 + c15;
        float bias = gl0_b[col];
        f32x4 ac0 = {bias,bias,bias,bias}, ac1 = ac0, ac2 = ac0, ac3 = ac0;
        #pragma unroll
        for (int S = 0; S < 5; ++S){
            int koff = S*64 + half*16;
            uint4 a0 = *(const uint4*)(Lb + A0B + (0*16 + c15)*384 + (koff ^ swzc));
            uint4 a1 = *(const uint4*)(Lb + A0B + (1*16 + c15)*384 + (koff ^ swzc));
            uint4 a2 = *(const uint4*)(Lb + A0B + (2*16 + c15)*384 + (koff ^ swzc));
            uint4 a3 = *(const uint4*)(Lb + A0B + (3*16 + c15)*384 + (koff ^ swzc));
            ac0 = MFMA(a0, bfr[S], ac0);
            ac1 = MFMA(a1, bfr[S], ac1);
            ac2 = MFMA(a2, bfr[S], ac2);
            ac3 = MFMA(a3, bfr[S], ac3);
        }
        const int off = col * 2;
        #pragma unroll
        for (int r = 0; r < 4; ++r){
            int row0 = 0*16 + half*4 + r;
            int row1 = 1*16 + half*4 + r;
            int row2 = 2*16 + half*4 + r;
            int row3 = 3*16 + half*4 + r;
            *(bf16*)(Lb + A1B + row0*128 + (off ^ ((row0 & 7) << 4))) = __float2bfloat16(fmaxf(ac0[r], 0.f));
            *(bf16*)(Lb + A1B + row1*128 + (off ^ ((row1 & 7) << 4))) = __float2bfloat16(fmaxf(ac1[r], 0.f));
            *(bf16*)(Lb + A1B + row2*128 + (off ^ ((row2 & 7) << 4))) = __float2bfloat16(fmaxf(ac2[r], 0.f));
            *(bf16*)(Lb + A1B + row3*128 + (off ^ ((row3 & 7) << 4))) = __float2bfloat16(fmaxf(ac3[r], 0.f));
        }
    }
    __syncthreads();

    // ---------- phase 3: gl1 MFMA (A1 -> A0 region, stride 128B) ----------
    {
        uint4 bfr[2];
        #pragma unroll
        for (int S = 0; S < 2; ++S) bfr[S] = packW[PK_GL1 + (w*2 + S)*64 + lane];
        const int col = w * 16 + c15;
        float bias = gl1_b[col];
        f32x4 ac0 = {bias,bias,bias,bias}, ac1 = ac0, ac2 = ac0, ac3 = ac0;
        #pragma unroll
        for (int S = 0; S < 2; ++S){
            int koff = S*64 + half*16;
            uint4 a0 = *(const uint4*)(Lb + A1B + (0*16 + c15)*128 + (koff ^ swzc));
            uint4 a1 = *(const uint4*)(Lb + A1B + (1*16 + c15)*128 + (koff ^ swzc));
            uint4 a2 = *(const uint4*)(Lb + A1B + (2*16 + c15)*128 + (koff ^ swzc));
            uint4 a3 = *(const uint4*)(Lb + A1B + (3*16 + c15)*128 + (koff ^ swzc));
            ac0 = MFMA(a0, bfr[S], ac0);
            ac1 = MFMA(a1, bfr[S], ac1);
            ac2 = MFMA(a2, bfr[S], ac2);
            ac3 = MFMA(a3, bfr[S], ac3);
        }
        const int off = col * 2;
        #pragma unroll
        for (int r = 0; r < 4; ++r){
            int row0 = 0*16 + half*4 + r;
            int row1 = 1*16 + half*4 + r;
            int row2 = 2*16 + half*4 + r;
            int row3 = 3*16 + half*4 + r;
            *(bf16*)(Lb + A0B + row0*128 + (off ^ ((row0 & 7) << 4))) = __float2bfloat16(fmaxf(ac0[r], 0.f));
            *(bf16*)(Lb + A0B + row1*128 + (off ^ ((row1 & 7) << 4))) = __float2bfloat16(fmaxf(ac1[r], 0.f));
            *(bf16*)(Lb + A0B + row2*128 + (off ^ ((row2 & 7) << 4))) = __float2bfloat16(fmaxf(ac2[r], 0.f));
            *(bf16*)(Lb + A0B + row3*128 + (off ^ ((row3 & 7) << 4))) = __float2bfloat16(fmaxf(ac3[r], 0.f));
        }
    }
    __syncthreads();

    // ---------- phase 4: gl2 MFMA (wave w -> rowblk w) + src build into A1 ----------
    {
        uint4 bfr[2];
        #pragma unroll
        for (int S = 0; S < 2; ++S) bfr[S] = packW[PK_GL2 + S*64 + lane];
        float bias = gl2_b[c15];
        f32x4 ac = {bias,bias,bias,bias};
        #pragma unroll
        for (int S = 0; S < 2; ++S){
            int koff = S*64 + half*16;
            uint4 a = *(const uint4*)(Lb + A0B + (w*16 + c15)*128 + (koff ^ swzc));
            ac = MFMA(a, bfr[S], ac);
        }
        const float* pef = (const float*)&L[PE_OFFD];
        const int off = (48 + c15) * 2;
        #pragma unroll
        for (int r = 0; r < 4; ++r){
            int row = w*16 + half*4 + r;
            float v = fmaxf(ac[r], 0.f) + pef[row];
            *(bf16*)(Lb + A1B + row*128 + (off ^ ((row & 7) << 4))) = __float2bfloat16(v);
        }

        // emb_act / emb_zone / od -> src cols 0..47
        float pe = pef[lane];
        const float* hd = (const float*)&L[HEAD_OFFD + lane * 8];
        int ia = (int)hd[0], iz = (int)hd[1];
        const int tswz = (lane & 7) << 4;
        #pragma unroll
        for (int pp = 0; pp < 6; ++pp){
            int p = w * 6 + pp;
            int c0 = 2 * p;
            float v0, v1;
            if (p < 8)        { v0 = emb_act[ia*16 + c0];        v1 = emb_act[ia*16 + c0 + 1]; }
            else if (p < 16)  { v0 = emb_zone[iz*16 + c0 - 16];  v1 = emb_zone[iz*16 + c0 - 15]; }
            else {
                int cc = c0 - 32;
                float o0 = lin0_b[cc], o1 = lin0_b[cc+1];
                #pragma unroll
                for (int e = 0; e < 6; ++e){
                    float f = hd[2 + e];
                    o0 = fmaf(f, lin0_W[e*16 + cc], o0);
                    o1 = fmaf(f, lin0_W[e*16 + cc + 1], o1);
                }
                v0 = o0; v1 = o1;
            }
            *(unsigned*)(Lb + A1B + lane*128 + ((4*p) ^ tswz)) = pk2(v0 + pe, v1 + pe);
        }
    }
    __syncthreads();

    // ---------- phase 5: src_last + KV MFMA ----------
    {
        int r0 = 39 - (blk0 % 40);
        if (t < 128){
            int tok = r0 + 40 * (t >> 6);
            if (tok < 64){
                int col = t & 63;
                bf16 hv = *(const bf16*)(Lb + A1B + tok*128 + ((col*2) ^ ((tok & 7) << 4)));
                src_last[(size_t)((blk0 + tok) / 40) * 64 + col] = __bfloat162float(hv);
            }
        }

        uint4 bfk[2][2];
        #pragma unroll
        for (int cf = 0; cf < 2; ++cf)
            #pragma unroll
            for (int S = 0; S < 2; ++S)
                bfk[cf][S] = packW[PK_KV + ((w*2 + cf)*2 + S)*64 + lane];

        float b0v = bqkv[64 + w*32 + c15];
        float b1v = bqkv[64 + w*32 + 16 + c15];
        f32x4 acc[4][2];
        #pragma unroll
        for (int R = 0; R < 4; ++R){
            acc[R][0] = (f32x4){b0v, b0v, b0v, b0v};
            acc[R][1] = (f32x4){b1v, b1v, b1v, b1v};
        }
        #pragma unroll
        for (int S = 0; S < 2; ++S){
            int koff = S*64 + half*16;
            #pragma unroll
            for (int R = 0; R < 4; ++R){
                uint4 a = *(const uint4*)(Lb + A1B + (R*16 + c15)*128 + (koff ^ swzc));
                acc[R][0] = MFMA(a, bfk[0][S], acc[R][0]);
                acc[R][1] = MFMA(a, bfk[1][S], acc[R][1]);
            }
        }
        #pragma unroll
        for (int R = 0; R < 4; ++R){
            #pragma unroll
            for (int cf = 0; cf < 2; ++cf){
                int lcol = w*32 + cf*16 + c15;
                int off = lcol * 2;
                #pragma unroll
                for (int r = 0; r < 4; ++r){
                    int row = R*16 + half*4 + r;
                    *(bf16*)(Lb + A0B + row*256 + (off ^ ((row & 7) << 4))) = __float2bfloat16(acc[R][cf][r]);
                }
            }
        }
    }
    __syncthreads();

    // coalesced KV store
    {
        int row = t >> 2;
        int q = t & 3;
        #pragma unroll
        for (int c = 0; c < 4; ++c){
            int chunk = q*4 + c;
            uint4 d = *(const uint4*)(Lb + A0B + row*256 + ((chunk*16) ^ ((row & 7) << 4)));
            *((uint4*)(kv + (size_t)(blk0 + row) * 128 + chunk * 8)) = d;
        }
    }
}

// ---------------- Kernel 2: per-batch attention@last + FFN + heads (2 batches/block) ----------------
__global__ __launch_bounds__(256) void k_head(
    const bf16* __restrict__ kv, const float* __restrict__ src_last,
    const float* __restrict__ Wqkv, const float* __restrict__ bqkv,
    const float* __restrict__ Wo,   const float* __restrict__ bo,
    const float* __restrict__ ln1_g, const float* __restrict__ ln1_b,
    const float* __restrict__ W1,   const float* __restrict__ b1,
    const float* __restrict__ W2,   const float* __restrict__ b2,
    const float* __restrict__ ln2_g, const float* __restrict__ ln2_b,
    const float* __restrict__ relu_W, const float* __restrict__ relu_b,
    const float* __restrict__ nd_W, const float* __restrict__ nd_b,
    const float* __restrict__ ldt_W, const float* __restrict__ ldt_b,
    const float* __restrict__ nz_W, const float* __restrict__ nz_b,
    const float* __restrict__ lz_W, const float* __restrict__ lz_b,
    const float* __restrict__ na0_W, const float* __restrict__ na0_b,
    const float* __restrict__ na1_W, const float* __restrict__ na1_b,
    const float* __restrict__ la_W, const float* __restrict__ la_b,
    float* __restrict__ out)
{
    const int hf = threadIdx.x >> 7;     // which batch half
    const int t  = threadIdx.x & 127;
    const int b  = blockIdx.x * 2 + hf;

    __shared__ float kb[2][40][64];
    __shared__ float vb[2][40][64];
    __shared__ float qs[2][64], xb[2][64], yb[2][64], f1[2][256];
    __shared__ float xrs[2][64], m65[2][65], mzs[2][20], fa1[2][85], fa2[2][85], redv[2];

    {
        const unsigned* kv32 = (const unsigned*)(kv + (size_t)b * 40 * 128);
        for (int idx = t; idx < 2560; idx += 128){
            unsigned u = kv32[idx];
            int j  = idx >> 6;
            int cp = (idx & 63) << 1;
            float lo = __uint_as_float(u << 16);
            float hi = __uint_as_float(u & 0xffff0000u);
            if (cp < 64){ kb[hf][j][cp] = lo; kb[hf][j][cp+1] = hi; }
            else        { vb[hf][j][cp-64] = lo; vb[hf][j][cp-63] = hi; }
        }
    }
    if (t < 64) xb[hf][t] = src_last[b*64 + t];
    __syncthreads();

    if (t < 64){
        float a = bqkv[t];
        for (int d = 0; d < 64; ++d) a += xb[hf][d]*Wqkv[d*192 + t];
        qs[hf][t] = a * 0.35355339059327373f;
    }
    __syncthreads();

    float o_c = 0.f;
    if (t < 64){
        const int h = t >> 3;
        const float* qh = &qs[hf][h*8];
        float sc[40];
        float m = -1e30f;
        #pragma unroll
        for (int j = 0; j < 40; ++j){
            float a = 0.f;
            #pragma unroll
            for (int d = 0; d < 8; ++d) a += qh[d]*kb[hf][j][h*8+d];
            sc[j] = a; m = fmaxf(m, a);
        }
        float Z = 0.f, acc = 0.f;
        #pragma unroll
        for (int j = 0; j < 40; ++j){
            float w = __expf(sc[j] - m);
            Z += w; acc += w * vb[hf][j][t];
        }
        o_c = acc / Z;
    }
    if (t < 64) yb[hf][t] = o_c;
    __syncthreads();

    float x1 = 0.f;
    if (t < 64){
        float a = bo[t];
        for (int d = 0; d < 64; ++d) a += yb[hf][d]*Wo[d*64+t];
        float v = xb[hf][t] + a;
        float sum = v;
        #pragma unroll
        for (int off = 1; off < 64; off <<= 1) sum += __shfl_xor(sum, off, 64);
        float mean = sum * (1.f/64.f);
        float dd = v - mean;
        float s2 = dd*dd;
        #pragma unroll
        for (int off = 1; off < 64; off <<= 1) s2 += __shfl_xor(s2, off, 64);
        float var = s2 * (1.f/64.f);
        x1 = dd * rsqrtf(var + 1e-5f) * ln1_g[t] + ln1_b[t];
    }
    __syncthreads();
    if (t < 64) xb[hf][t] = x1;
    __syncthreads();

    for (int c = t; c < 256; c += 128){
        float a = b1[c];
        for (int d = 0; d < 64; ++d) a += xb[hf][d]*W1[d*256+c];
        f1[hf][c] = fmaxf(a, 0.f);
    }
    __syncthreads();

    if (t < 64){
        float a = b2[t];
        for (int j = 0; j < 256; ++j) a += f1[hf][j]*W2[j*64+t];
        float v = xb[hf][t] + a;
        float sum = v;
        #pragma unroll
        for (int off = 1; off < 64; off <<= 1) sum += __shfl_xor(sum, off, 64);
        float mean = sum * (1.f/64.f);
        float dd = v - mean;
        float s2 = dd*dd;
        #pragma unroll
        for (int off = 1; off < 64; off <<= 1) s2 += __shfl_xor(s2, off, 64);
        float var = s2 * (1.f/64.f);
        yb[hf][t] = dd * rsqrtf(var + 1e-5f) * ln2_g[t] + ln2_b[t];
    }
    __syncthreads();

    if (t < 64){
        float a = relu_b[t];
        for (int d = 0; d < 64; ++d) a += yb[hf][d]*relu_W[d*64+t];
        xrs[hf][t] = a;
    }
    __syncthreads();

    if (t < 64){
        float a = nd_b[t];
        for (int d = 0; d < 64; ++d) a += xrs[hf][d]*nd_W[d*64+t];
        float contrib = a * ldt_W[t];
        #pragma unroll
        for (int off = 1; off < 64; off <<= 1) contrib += __shfl_xor(contrib, off, 64);
        if (t == 0) redv[hf] = contrib + ldt_b[0];
    }
    __syncthreads();
    float dT = redv[hf];

    if (t < 65){
        float a = nz_b[t] + dT*nz_W[t];
        for (int d = 0; d < 64; ++d) a += xrs[hf][d]*nz_W[(1+d)*65+t];
        m65[hf][t] = a;
    }
    __syncthreads();

    if (t < 20){
        float a = lz_b[t];
        for (int d = 0; d < 65; ++d) a += m65[hf][d]*lz_W[d*20+t];
        mzs[hf][t] = a;
    }
    __syncthreads();

    if (t < 85){
        float a = na0_b[t];
        for (int d = 0; d < 20; ++d) a += mzs[hf][d]*na0_W[d*85+t];
        a += dT*na0_W[20*85+t];
        for (int d = 0; d < 64; ++d) a += xrs[hf][d]*na0_W[(21+d)*85+t];
        fa1[hf][t] = a;
    }
    __syncthreads();
    if (t < 85){
        float a = na1_b[t];
        for (int d = 0; d < 85; ++d) a += fa1[hf][d]*na1_W[d*85+t];
        fa2[hf][t] = a;
    }
    __syncthreads();

    if (t == 0) out[b*26] = dT;
    if (t < 20) out[b*26 + 1 + t] = mzs[hf][t];
    if (t < 5){
        float a = la_b[t];
        for (int d = 0; d < 85; ++d) a += fa2[hf][d]*la_W[d*5+t];
        out[b*26 + 21 + t] = a;
    }
}

extern "C" void kernel_launch(void* const* d_in, const int* in_sizes, int n_in,
                              void* d_out, int out_size, void* d_ws, size_t ws_size,
                              hipStream_t stream)
{
    const float* X        = (const float*)d_in[0];
    const float* emb_act  = (const float*)d_in[1];
    const float* emb_zone = (const float*)d_in[2];
    const float* lin0_W   = (const float*)d_in[3];
    const float* lin0_b   = (const float*)d_in[4];
    const float* gat_W    = (const float*)d_in[5];
    const float* gat_b    = (const float*)d_in[6];
    const float* gat_a    = (const float*)d_in[7];
    const float* gl0_W    = (const float*)d_in[8];
    const float* gl0_b    = (const float*)d_in[9];
    const float* gl1_W    = (const float*)d_in[10];
    const float* gl1_b    = (const float*)d_in[11];
    const float* gl2_W    = (const float*)d_in[12];
    const float* gl2_b    = (const float*)d_in[13];
    const float* Wqkv     = (const float*)d_in[14];
    const float* bqkv     = (const float*)d_in[15];
    const float* Wo       = (const float*)d_in[16];
    const float* bo       = (const float*)d_in[17];
    const float* ln1_g    = (const float*)d_in[18];
    const float* ln1_b    = (const float*)d_in[19];
    const float* W1       = (const float*)d_in[20];
    const float* b1       = (const float*)d_in[21];
    const float* W2       = (const float*)d_in[22];
    const float* b2       = (const float*)d_in[23];
    const float* ln2_g    = (const float*)d_in[24];
    const float* ln2_b    = (const float*)d_in[25];
    const float* relu_W   = (const float*)d_in[26];
    const float* relu_b   = (const float*)d_in[27];
    const float* nd_W     = (const float*)d_in[28];
    const float* nd_b     = (const float*)d_in[29];
    const float* ldt_W    = (const float*)d_in[30];
    const float* ldt_b    = (const float*)d_in[31];
    const float* nz_W     = (const float*)d_in[32];
    const float* nz_b     = (const float*)d_in[33];
    const float* lz_W     = (const float*)d_in[34];
    const float* lz_b     = (const float*)d_in[35];
    const float* na0_W    = (const float*)d_in[36];
    const float* na0_b    = (const float*)d_in[37];
    const float* na1_W    = (const float*)d_in[38];
    const float* na1_b    = (const float*)d_in[39];
    const float* la_W     = (const float*)d_in[40];
    const float* la_b     = (const float*)d_in[41];

    bf16*  kv       = (bf16*)d_ws;
    float* src_last = (float*)((char*)d_ws + (size_t)NTOK * 128 * sizeof(bf16));
    uint4* packW    = (uint4*)((char*)d_ws + (size_t)NTOK * 128 * sizeof(bf16) + (size_t)B_ * 64 * sizeof(float));

    k_pack<<<(PK_TOT + 255)/256, 256, 0, stream>>>(gl0_W, gl1_W, gl2_W, Wqkv, packW);

    k_token<<<NTOK/TOKB, TPB, 0, stream>>>(X, emb_act, emb_zone, lin0_W, lin0_b,
        gat_W, gat_b, gat_a, gl0_b, gl1_b, gl2_b, bqkv, packW, kv, src_last);

    k_head<<<B_/2, 256, 0, stream>>>(kv, src_last, Wqkv, bqkv, Wo, bo,
        ln1_g, ln1_b, W1, b1, W2, b2, ln2_g, ln2_b, relu_W, relu_b,
        nd_W, nd_b, ldt_W, ldt_b, nz_W, nz_b, lz_W, lz_b,
        na0_W, na0_b, na1_W, na1_b, la_W, la_b, (float*)d_out);
}